// Round 4
// baseline (269.279 us; speedup 1.0000x reference)
//
#include <hip/hip_runtime.h>
#include <math.h>

// Shapes: B=8, N=256, NID=64, V=GH=128, PHI=256, RHO=128
#define NB 8
#define NN 256
#define DV 128

// ---------------------------------------------------------------------------
// k_embed: H = relu(X@w1+b1)@w2+b2.  8 rows/block, grid 256, 256 thr.
// f = t&127; hh = t>>7 splits the k-range (split-k), combine via LDS.
// Also zeroes the pooling buffers (blocks 0..15).
// ---------------------------------------------------------------------------
__global__ __launch_bounds__(256) void k_embed(const float* __restrict__ X,
        const float* __restrict__ w1, const float* __restrict__ b1,
        const float* __restrict__ w2, const float* __restrict__ b2,
        float* __restrict__ H, float* __restrict__ pools) {
    const int r0 = blockIdx.x * 8;
    const int t = threadIdx.x, f = t & 127, hh = t >> 7;
    __shared__ __align__(16) float xq[64 * 8];    // [k][r]
    __shared__ __align__(16) float h1q[128 * 8];  // [k][r]
    __shared__ __align__(16) float pp[8 * 128];   // half-1 partials
    if (blockIdx.x < 16) pools[blockIdx.x * 256 + t] = 0.f;
    #pragma unroll
    for (int p = 0; p < 2; ++p) {
        int idx = p * 256 + t;
        int k = idx >> 3, r = idx & 7;
        xq[k * 8 + r] = X[(size_t)(r0 + r) * 64 + k];
    }
    __syncthreads();
    float acc[8];
    #pragma unroll
    for (int r = 0; r < 8; ++r) acc[r] = 0.f;
    #pragma unroll 8
    for (int kk = 0; kk < 32; ++kk) {
        int k = hh * 32 + kk;
        float w = w1[k * 128 + f];
        float4 xA = *(const float4*)&xq[k * 8];
        float4 xB = *(const float4*)&xq[k * 8 + 4];
        acc[0] = fmaf(xA.x, w, acc[0]); acc[1] = fmaf(xA.y, w, acc[1]);
        acc[2] = fmaf(xA.z, w, acc[2]); acc[3] = fmaf(xA.w, w, acc[3]);
        acc[4] = fmaf(xB.x, w, acc[4]); acc[5] = fmaf(xB.y, w, acc[5]);
        acc[6] = fmaf(xB.z, w, acc[6]); acc[7] = fmaf(xB.w, w, acc[7]);
    }
    if (hh) {
        #pragma unroll
        for (int r = 0; r < 8; ++r) pp[r * 128 + f] = acc[r];
    }
    __syncthreads();
    if (!hh) {
        #pragma unroll
        for (int r = 0; r < 8; ++r)
            h1q[f * 8 + r] = fmaxf(acc[r] + pp[r * 128 + f] + b1[f], 0.f);
    }
    __syncthreads();
    float a2[8];
    #pragma unroll
    for (int r = 0; r < 8; ++r) a2[r] = 0.f;
    #pragma unroll 8
    for (int kk = 0; kk < 64; ++kk) {
        int k = hh * 64 + kk;
        float w = w2[k * 128 + f];
        float4 hA = *(const float4*)&h1q[k * 8];
        float4 hB = *(const float4*)&h1q[k * 8 + 4];
        a2[0] = fmaf(hA.x, w, a2[0]); a2[1] = fmaf(hA.y, w, a2[1]);
        a2[2] = fmaf(hA.z, w, a2[2]); a2[3] = fmaf(hA.w, w, a2[3]);
        a2[4] = fmaf(hB.x, w, a2[4]); a2[5] = fmaf(hB.y, w, a2[5]);
        a2[6] = fmaf(hB.z, w, a2[6]); a2[7] = fmaf(hB.w, w, a2[7]);
    }
    if (hh) {
        #pragma unroll
        for (int r = 0; r < 8; ++r) pp[r * 128 + f] = a2[r];
    }
    __syncthreads();
    if (!hh) {
        #pragma unroll
        for (int r = 0; r < 8; ++r)
            H[(size_t)(r0 + r) * 128 + f] = a2[r] + pp[r * 128 + f] + b2[f];
    }
}

// ---------------------------------------------------------------------------
// k_gcn1 = relation-mean aggregation + RGCN linear, fused.
// Block = (b, 8 target cols j). Masks/counts computed inline from A.
// Phase A: means over i (split-i halves); Phase B: 3-matrix GEMM (split-k).
// H rows are read straight from L2 (16-deep load batches), each row once.
// ---------------------------------------------------------------------------
__global__ __launch_bounds__(256) void k_gcn1(
        const float* __restrict__ A, const float* __restrict__ H,
        const float* __restrict__ Wrel, const float* __restrict__ Wroot,
        const float* __restrict__ bias, float* __restrict__ H2) {
    const int b  = blockIdx.x >> 5;
    const int j0 = (blockIdx.x & 31) * 8;
    const int t = threadIdx.x, f = t & 127, hh = t >> 7;
    __shared__ __align__(16) float ldsM[256 * 16];  // [i][rel*8+r]; alias: partials
    __shared__ __align__(16) float pb[128 * 24];    // [k][h8|m0_8|m1_8]
    __shared__ float cntp[256];                     // [slot*16+chunk]
    __shared__ float cnt[16];                       // [rel*8+r]
    float* P = ldsM;                                // partial-combine region
    const float* Ab = A + (size_t)b * NN * NN;
    const float* Hb = H + (size_t)b * NN * DV;

    // masks from A columns j0..j0+7
    #pragma unroll
    for (int p = 0; p < 8; ++p) {
        int idx = p * 256 + t;
        int i = idx >> 3, r = idx & 7;
        float a = Ab[(size_t)i * 256 + j0 + r];
        ldsM[i * 16 + r]     = (a < 0.f) ? 1.f : 0.f;
        ldsM[i * 16 + 8 + r] = (a > 0.f) ? 1.f : 0.f;
    }
    __syncthreads();
    // count partials (16 chunks x 16 slots)
    {
        int chunk = t >> 4, slot = t & 15;
        float c = 0.f;
        #pragma unroll
        for (int q = 0; q < 16; ++q)
            c += ldsM[(chunk * 16 + q) * 16 + slot];
        cntp[slot * 16 + chunk] = c;
    }
    // phase A: masked sums, i in [hh*128, hh*128+128)
    float a0[8], a1[8];
    #pragma unroll
    for (int r = 0; r < 8; ++r) { a0[r] = 0.f; a1[r] = 0.f; }
    for (int gg = 0; gg < 8; ++gg) {
        const int ibase = hh * 128 + gg * 16;
        float hv[16];
        #pragma unroll
        for (int u = 0; u < 16; ++u)
            hv[u] = Hb[(size_t)(ibase + u) * 128 + f];
        #pragma unroll
        for (int u = 0; u < 16; ++u) {
            const float* mp = &ldsM[(ibase + u) * 16];
            float4 m0a = *(const float4*)mp;
            float4 m0b = *(const float4*)(mp + 4);
            float4 m1a = *(const float4*)(mp + 8);
            float4 m1b = *(const float4*)(mp + 12);
            float h = hv[u];
            a0[0] = fmaf(m0a.x, h, a0[0]); a0[1] = fmaf(m0a.y, h, a0[1]);
            a0[2] = fmaf(m0a.z, h, a0[2]); a0[3] = fmaf(m0a.w, h, a0[3]);
            a0[4] = fmaf(m0b.x, h, a0[4]); a0[5] = fmaf(m0b.y, h, a0[5]);
            a0[6] = fmaf(m0b.z, h, a0[6]); a0[7] = fmaf(m0b.w, h, a0[7]);
            a1[0] = fmaf(m1a.x, h, a1[0]); a1[1] = fmaf(m1a.y, h, a1[1]);
            a1[2] = fmaf(m1a.z, h, a1[2]); a1[3] = fmaf(m1a.w, h, a1[3]);
            a1[4] = fmaf(m1b.x, h, a1[4]); a1[5] = fmaf(m1b.y, h, a1[5]);
            a1[6] = fmaf(m1b.z, h, a1[6]); a1[7] = fmaf(m1b.w, h, a1[7]);
        }
    }
    __syncthreads();
    // half-1 dumps partial sums into P (masks now dead); counts finalized
    if (hh) {
        #pragma unroll
        for (int s = 0; s < 8; ++s) {
            P[s * 128 + f] = a0[s];
            P[(s + 8) * 128 + f] = a1[s];
        }
    }
    if (t < 16) {
        float s = 0.f;
        #pragma unroll
        for (int c = 0; c < 16; ++c) s += cntp[t * 16 + c];
        cnt[t] = s;
    }
    __syncthreads();
    if (!hh) {
        #pragma unroll
        for (int s = 0; s < 16; ++s) {
            float tot = ((s < 8) ? a0[s] : a1[s - 8]) + P[s * 128 + f];
            pb[f * 24 + 8 + s] = tot / fmaxf(cnt[s], 1.f);
        }
    } else {
        #pragma unroll
        for (int r = 0; r < 8; ++r)
            pb[f * 24 + r] = Hb[(size_t)(j0 + r) * 128 + f];
    }
    __syncthreads();
    // phase B: H2 rows = h@Wroot + m0@W0 + m1@W1 (+bias), split-k halves
    const float* W0 = Wrel;
    const float* W1 = Wrel + 128 * 128;
    float bcc[8];
    #pragma unroll
    for (int r = 0; r < 8; ++r) bcc[r] = 0.f;
    #pragma unroll 8
    for (int kk = 0; kk < 64; ++kk) {
        int k = hh * 64 + kk;
        float wr = Wroot[k * 128 + f];
        float w0 = W0[k * 128 + f];
        float w1 = W1[k * 128 + f];
        const float* pk = &pb[k * 24];
        float4 hA = *(const float4*)pk;
        float4 hB = *(const float4*)(pk + 4);
        float4 qA = *(const float4*)(pk + 8);
        float4 qB = *(const float4*)(pk + 12);
        float4 rA = *(const float4*)(pk + 16);
        float4 rB = *(const float4*)(pk + 20);
        bcc[0] = fmaf(hA.x, wr, bcc[0]); bcc[0] = fmaf(qA.x, w0, bcc[0]); bcc[0] = fmaf(rA.x, w1, bcc[0]);
        bcc[1] = fmaf(hA.y, wr, bcc[1]); bcc[1] = fmaf(qA.y, w0, bcc[1]); bcc[1] = fmaf(rA.y, w1, bcc[1]);
        bcc[2] = fmaf(hA.z, wr, bcc[2]); bcc[2] = fmaf(qA.z, w0, bcc[2]); bcc[2] = fmaf(rA.z, w1, bcc[2]);
        bcc[3] = fmaf(hA.w, wr, bcc[3]); bcc[3] = fmaf(qA.w, w0, bcc[3]); bcc[3] = fmaf(rA.w, w1, bcc[3]);
        bcc[4] = fmaf(hB.x, wr, bcc[4]); bcc[4] = fmaf(qB.x, w0, bcc[4]); bcc[4] = fmaf(rB.x, w1, bcc[4]);
        bcc[5] = fmaf(hB.y, wr, bcc[5]); bcc[5] = fmaf(qB.y, w0, bcc[5]); bcc[5] = fmaf(rB.y, w1, bcc[5]);
        bcc[6] = fmaf(hB.z, wr, bcc[6]); bcc[6] = fmaf(qB.z, w0, bcc[6]); bcc[6] = fmaf(rB.z, w1, bcc[6]);
        bcc[7] = fmaf(hB.w, wr, bcc[7]); bcc[7] = fmaf(qB.w, w0, bcc[7]); bcc[7] = fmaf(rB.w, w1, bcc[7]);
    }
    if (hh) {
        #pragma unroll
        for (int r = 0; r < 8; ++r) P[r * 128 + f] = bcc[r];
    }
    __syncthreads();
    if (!hh) {
        #pragma unroll
        for (int r = 0; r < 8; ++r)
            H2[(size_t)(b * 256 + j0 + r) * 128 + f] =
                bcc[r] + P[r * 128 + f] + bias[f];
    }
}

// ---------------------------------------------------------------------------
// k_gcn2 = |A|-aggregation + LayerNorm + 2-layer MLP + H-update, fused.
// Block = (b, 8 source rows i). H2 rows read from L2 in 16-deep batches.
// ---------------------------------------------------------------------------
__global__ __launch_bounds__(256) void k_gcn2(
        const float* __restrict__ A, const float* __restrict__ H2,
        const float* __restrict__ g, const float* __restrict__ bta,
        const float* __restrict__ law, const float* __restrict__ lab,
        const float* __restrict__ lbw, const float* __restrict__ lbb,
        float* __restrict__ H) {
    const int b  = blockIdx.x >> 5;
    const int i0 = (blockIdx.x & 31) * 8;
    const int t = threadIdx.x, f = t & 127, hh = t >> 7;
    __shared__ __align__(16) float ldsA[256 * 8];   // [j][r]; alias: partials
    __shared__ __align__(16) float xq[128 * 8];     // [k][r]
    __shared__ __align__(16) float uq[128 * 8];     // [k][r]
    __shared__ float red[32];
    __shared__ float mi[16];
    float* P = ldsA;
    const float* Ab  = A + (size_t)b * NN * NN;
    const float* H2b = H2 + (size_t)b * NN * DV;

    #pragma unroll
    for (int p = 0; p < 8; ++p)
        ldsA[t * 8 + p] = fabsf(Ab[(size_t)(i0 + p) * 256 + t]);
    __syncthreads();
    // aggregation: agg[r,f] = sum_j |A[i0+r, j]| * H2[j, f]  (split-j halves)
    float acc[8];
    #pragma unroll
    for (int r = 0; r < 8; ++r) acc[r] = 0.f;
    for (int gg = 0; gg < 8; ++gg) {
        const int jbase = hh * 128 + gg * 16;
        float hv[16];
        #pragma unroll
        for (int u = 0; u < 16; ++u)
            hv[u] = H2b[(size_t)(jbase + u) * 128 + f];
        #pragma unroll
        for (int u = 0; u < 16; ++u) {
            const float* ap = &ldsA[(jbase + u) * 8];
            float4 aA = *(const float4*)ap;
            float4 aB = *(const float4*)(ap + 4);
            float h = hv[u];
            acc[0] = fmaf(aA.x, h, acc[0]); acc[1] = fmaf(aA.y, h, acc[1]);
            acc[2] = fmaf(aA.z, h, acc[2]); acc[3] = fmaf(aA.w, h, acc[3]);
            acc[4] = fmaf(aB.x, h, acc[4]); acc[5] = fmaf(aB.y, h, acc[5]);
            acc[6] = fmaf(aB.z, h, acc[6]); acc[7] = fmaf(aB.w, h, acc[7]);
        }
    }
    __syncthreads();
    if (hh) {
        #pragma unroll
        for (int r = 0; r < 8; ++r) P[r * 128 + f] = acc[r];
    }
    __syncthreads();
    float x[8];
    if (!hh) {
        const int wv = t >> 6;
        #pragma unroll
        for (int r = 0; r < 8; ++r) {
            x[r] = acc[r] + P[r * 128 + f];
            float s = x[r], s2 = x[r] * x[r];
            #pragma unroll
            for (int o = 32; o > 0; o >>= 1) {
                s  += __shfl_down(s, o, 64);
                s2 += __shfl_down(s2, o, 64);
            }
            if ((t & 63) == 0) { red[r * 4 + wv * 2] = s; red[r * 4 + wv * 2 + 1] = s2; }
        }
    }
    __syncthreads();
    if (t < 8) {
        float s  = red[t * 4] + red[t * 4 + 2];
        float s2 = red[t * 4 + 1] + red[t * 4 + 3];
        float m = s * (1.f / 128.f);
        float v = s2 * (1.f / 128.f) - m * m;
        mi[t * 2] = m;
        mi[t * 2 + 1] = rsqrtf(v + 1e-5f);
    }
    __syncthreads();
    if (!hh) {
        #pragma unroll
        for (int r = 0; r < 8; ++r)
            xq[f * 8 + r] =
                fmaxf((x[r] - mi[r * 2]) * mi[r * 2 + 1] * g[f] + bta[f], 0.f);
    }
    __syncthreads();
    // MLP layer A (split-k)
    float u1[8];
    #pragma unroll
    for (int r = 0; r < 8; ++r) u1[r] = 0.f;
    #pragma unroll 8
    for (int kk = 0; kk < 64; ++kk) {
        int k = hh * 64 + kk;
        float w = law[k * 128 + f];
        float4 xA = *(const float4*)&xq[k * 8];
        float4 xB = *(const float4*)&xq[k * 8 + 4];
        u1[0] = fmaf(xA.x, w, u1[0]); u1[1] = fmaf(xA.y, w, u1[1]);
        u1[2] = fmaf(xA.z, w, u1[2]); u1[3] = fmaf(xA.w, w, u1[3]);
        u1[4] = fmaf(xB.x, w, u1[4]); u1[5] = fmaf(xB.y, w, u1[5]);
        u1[6] = fmaf(xB.z, w, u1[6]); u1[7] = fmaf(xB.w, w, u1[7]);
    }
    if (hh) {
        #pragma unroll
        for (int r = 0; r < 8; ++r) P[r * 128 + f] = u1[r];
    }
    __syncthreads();
    if (!hh) {
        #pragma unroll
        for (int r = 0; r < 8; ++r)
            uq[f * 8 + r] = fmaxf(u1[r] + P[r * 128 + f] + lab[f], 0.f);
    }
    __syncthreads();
    // MLP layer B (split-k)
    float u2[8];
    #pragma unroll
    for (int r = 0; r < 8; ++r) u2[r] = 0.f;
    #pragma unroll 8
    for (int kk = 0; kk < 64; ++kk) {
        int k = hh * 64 + kk;
        float w = lbw[k * 128 + f];
        float4 uA = *(const float4*)&uq[k * 8];
        float4 uB = *(const float4*)&uq[k * 8 + 4];
        u2[0] = fmaf(uA.x, w, u2[0]); u2[1] = fmaf(uA.y, w, u2[1]);
        u2[2] = fmaf(uA.z, w, u2[2]); u2[3] = fmaf(uA.w, w, u2[3]);
        u2[4] = fmaf(uB.x, w, u2[4]); u2[5] = fmaf(uB.y, w, u2[5]);
        u2[6] = fmaf(uB.z, w, u2[6]); u2[7] = fmaf(uB.w, w, u2[7]);
    }
    if (hh) {
        #pragma unroll
        for (int r = 0; r < 8; ++r) P[r * 128 + f] = u2[r];
    }
    __syncthreads();
    if (!hh) {
        #pragma unroll
        for (int r = 0; r < 8; ++r) {
            size_t o = (size_t)(b * 256 + i0 + r) * 128 + f;
            H[o] = H[o] + u2[r] + P[r * 128 + f] + lbb[f];
        }
    }
}

// ---------------------------------------------------------------------------
// k_deepset: phi (128->256->256 relu) + masked pooling.  8 rows/block,
// 256 threads, feature = t (4 waves cover distinct feature slices ->
// each weight matrix streamed exactly once per block).
// ---------------------------------------------------------------------------
__global__ __launch_bounds__(256) void k_deepset(
        const float* __restrict__ H, const float* __restrict__ hm,
        const float* __restrict__ w1, const float* __restrict__ b1,
        const float* __restrict__ w2, const float* __restrict__ b2,
        float* __restrict__ hsum, float* __restrict__ asum) {
    const int r0 = blockIdx.x * 8;
    const int b  = blockIdx.x >> 5;
    const int t  = threadIdx.x;
    __shared__ __align__(16) float hq[128 * 8];   // [k][r]
    __shared__ __align__(16) float phq[256 * 8];  // [k][r]
    __shared__ float hmv[8];
    #pragma unroll
    for (int p = 0; p < 4; ++p) {
        int idx = p * 256 + t;
        int k = idx >> 3, r = idx & 7;
        hq[k * 8 + r] = H[(size_t)(r0 + r) * 128 + k];
    }
    if (t < 8) hmv[t] = hm[r0 + t];
    __syncthreads();
    float acc[8];
    #pragma unroll
    for (int r = 0; r < 8; ++r) acc[r] = 0.f;
    #pragma unroll 16
    for (int k = 0; k < 128; ++k) {
        float w = w1[k * 256 + t];
        float4 hA = *(const float4*)&hq[k * 8];
        float4 hB = *(const float4*)&hq[k * 8 + 4];
        acc[0] = fmaf(hA.x, w, acc[0]); acc[1] = fmaf(hA.y, w, acc[1]);
        acc[2] = fmaf(hA.z, w, acc[2]); acc[3] = fmaf(hA.w, w, acc[3]);
        acc[4] = fmaf(hB.x, w, acc[4]); acc[5] = fmaf(hB.y, w, acc[5]);
        acc[6] = fmaf(hB.z, w, acc[6]); acc[7] = fmaf(hB.w, w, acc[7]);
    }
    #pragma unroll
    for (int r = 0; r < 8; ++r)
        phq[t * 8 + r] = fmaxf(acc[r] + b1[t], 0.f);
    __syncthreads();
    float a2[8];
    #pragma unroll
    for (int r = 0; r < 8; ++r) a2[r] = 0.f;
    #pragma unroll 16
    for (int k = 0; k < 256; ++k) {
        float w = w2[k * 256 + t];
        float4 pA = *(const float4*)&phq[k * 8];
        float4 pB = *(const float4*)&phq[k * 8 + 4];
        a2[0] = fmaf(pA.x, w, a2[0]); a2[1] = fmaf(pA.y, w, a2[1]);
        a2[2] = fmaf(pA.z, w, a2[2]); a2[3] = fmaf(pA.w, w, a2[3]);
        a2[4] = fmaf(pB.x, w, a2[4]); a2[5] = fmaf(pB.y, w, a2[5]);
        a2[6] = fmaf(pB.z, w, a2[6]); a2[7] = fmaf(pB.w, w, a2[7]);
    }
    float hp = 0.f, sp = 0.f;
    #pragma unroll
    for (int r = 0; r < 8; ++r) {
        float p = fmaxf(a2[r] + b2[t], 0.f);
        sp += p;
        hp = fmaf(p, hmv[r], hp);
    }
    atomicAdd(&hsum[b * 256 + t], hp);
    atomicAdd(&asum[b * 256 + t], sp - hp);
}

// ---------------------------------------------------------------------------
// k_rho: out[b] = 0.5 + 0.5*tanh(rho(home)-rho(away))
// ---------------------------------------------------------------------------
__global__ __launch_bounds__(128) void k_rho(const float* __restrict__ home_sum,
        const float* __restrict__ away_sum,
        const float* __restrict__ w1, const float* __restrict__ b1,
        const float* __restrict__ w2, const float* __restrict__ b2,
        float* __restrict__ out) {
    const int b = blockIdx.x;
    const int t = threadIdx.x;
    __shared__ float ws[2];
    float d[2];
    for (int which = 0; which < 2; ++which) {
        const float* s = (which == 0 ? home_sum : away_sum) + b * 256;
        float acc = b1[t];
        #pragma unroll 8
        for (int k = 0; k < 256; ++k) acc = fmaf(s[k], w1[k * 128 + t], acc);
        acc = fmaxf(acc, 0.f);
        float p = acc * w2[t];
        #pragma unroll
        for (int o = 32; o > 0; o >>= 1) p += __shfl_down(p, o, 64);
        if ((t & 63) == 0) ws[t >> 6] = p;
        __syncthreads();
        d[which] = ws[0] + ws[1] + b2[0];
        __syncthreads();
    }
    if (t == 0) out[b] = 0.5f + 0.5f * tanhf(d[0] - d[1]);
}

// ---------------------------------------------------------------------------
extern "C" void kernel_launch(void* const* d_in, const int* in_sizes, int n_in,
                              void* d_out, int out_size, void* d_ws, size_t ws_size,
                              hipStream_t stream) {
    const float* A         = (const float*)d_in[0];
    const float* X         = (const float*)d_in[1];
    const float* home_mask = (const float*)d_in[2];
    const float* emb1_w    = (const float*)d_in[3];
    const float* emb1_b    = (const float*)d_in[4];
    const float* emb2_w    = (const float*)d_in[5];
    const float* emb2_b    = (const float*)d_in[6];
    const float* rgcn_w[2]    = { (const float*)d_in[7],  (const float*)d_in[14] };
    const float* rgcn_root[2] = { (const float*)d_in[8],  (const float*)d_in[15] };
    const float* rgcn_bias[2] = { (const float*)d_in[9],  (const float*)d_in[16] };
    const float* lina_w[2]    = { (const float*)d_in[10], (const float*)d_in[17] };
    const float* lina_b[2]    = { (const float*)d_in[11], (const float*)d_in[18] };
    const float* linb_w[2]    = { (const float*)d_in[12], (const float*)d_in[19] };
    const float* linb_b[2]    = { (const float*)d_in[13], (const float*)d_in[20] };
    const float* norm_g  = (const float*)d_in[21];
    const float* norm_b  = (const float*)d_in[22];
    const float* phi_w1  = (const float*)d_in[23];
    const float* phi_b1  = (const float*)d_in[24];
    const float* phi_w2  = (const float*)d_in[25];
    const float* phi_b2  = (const float*)d_in[26];
    const float* rho_w1  = (const float*)d_in[27];
    const float* rho_b1  = (const float*)d_in[28];
    const float* rho_w2  = (const float*)d_in[29];
    const float* rho_b2  = (const float*)d_in[30];
    float* out = (float*)d_out;

    float* ws   = (float*)d_ws;
    float* H    = ws;               // 262144
    float* H2   = ws + 262144;      // 262144
    float* hsum = ws + 524288;      // 2048
    float* asum = ws + 526336;      // 2048 (contiguous with hsum)

    k_embed<<<256, 256, 0, stream>>>(X, emb1_w, emb1_b, emb2_w, emb2_b, H, hsum);

    for (int it = 0; it < 2; ++it) {
        k_gcn1<<<256, 256, 0, stream>>>(A, H, rgcn_w[it], rgcn_root[it],
                                        rgcn_bias[it], H2);
        k_gcn2<<<256, 256, 0, stream>>>(A, H2, norm_g, norm_b,
                                        lina_w[it], lina_b[it],
                                        linb_w[it], linb_b[it], H);
    }

    k_deepset<<<256, 256, 0, stream>>>(H, home_mask, phi_w1, phi_b1,
                                       phi_w2, phi_b2, hsum, asum);
    k_rho<<<NB, 128, 0, stream>>>(hsum, asum, rho_w1, rho_b1, rho_w2, rho_b2, out);
}

// Round 5
// 256.926 us; speedup vs baseline: 1.0481x; 1.0481x over previous
//
#include <hip/hip_runtime.h>
#include <math.h>

// Shapes: B=8, N=256, NID=64, V=GH=128, PHI=256, RHO=128
#define NB 8
#define NN 256
#define DV 128

// ---------------------------------------------------------------------------
// k_embed: H = relu(X@w1+b1)@w2+b2. 4 rows/block, grid 512, 256 thr.
// f = t&127; hh = t>>7 splits k-range; combine via LDS (P).
// Blocks 0..15 also zero the pooling buffers (4096 floats).
// ---------------------------------------------------------------------------
__global__ __launch_bounds__(256, 2) void k_embed(const float* __restrict__ X,
        const float* __restrict__ w1, const float* __restrict__ b1,
        const float* __restrict__ w2, const float* __restrict__ b2,
        float* __restrict__ H, float* __restrict__ pools) {
    const int r0 = blockIdx.x * 4;
    const int t = threadIdx.x, f = t & 127, hh = t >> 7;
    __shared__ __align__(16) float xq[64 * 4];
    __shared__ __align__(16) float h1q[128 * 4];
    __shared__ __align__(16) float P[4 * 128];
    if (blockIdx.x < 16) pools[blockIdx.x * 256 + t] = 0.f;
    if (t < 64) {
        float4 v;
        v.x = X[(size_t)(r0 + 0) * 64 + t];
        v.y = X[(size_t)(r0 + 1) * 64 + t];
        v.z = X[(size_t)(r0 + 2) * 64 + t];
        v.w = X[(size_t)(r0 + 3) * 64 + t];
        *(float4*)&xq[t * 4] = v;
    }
    __syncthreads();
    float acc[4] = {0.f, 0.f, 0.f, 0.f};
    #pragma unroll 1
    for (int gg = 0; gg < 2; ++gg) {
        const int kb = hh * 32 + gg * 16;
        float wl[16];
        #pragma unroll
        for (int u = 0; u < 16; ++u) wl[u] = w1[(kb + u) * 128 + f];
        #pragma unroll
        for (int u = 0; u < 16; ++u) {
            float4 xv = *(const float4*)&xq[(kb + u) * 4];
            acc[0] = fmaf(xv.x, wl[u], acc[0]); acc[1] = fmaf(xv.y, wl[u], acc[1]);
            acc[2] = fmaf(xv.z, wl[u], acc[2]); acc[3] = fmaf(xv.w, wl[u], acc[3]);
        }
    }
    if (hh) {
        #pragma unroll
        for (int r = 0; r < 4; ++r) P[r * 128 + f] = acc[r];
    }
    __syncthreads();
    if (!hh) {
        float4 h;
        h.x = fmaxf(acc[0] + P[0 * 128 + f] + b1[f], 0.f);
        h.y = fmaxf(acc[1] + P[1 * 128 + f] + b1[f], 0.f);
        h.z = fmaxf(acc[2] + P[2 * 128 + f] + b1[f], 0.f);
        h.w = fmaxf(acc[3] + P[3 * 128 + f] + b1[f], 0.f);
        *(float4*)&h1q[f * 4] = h;
    }
    __syncthreads();
    float a2[4] = {0.f, 0.f, 0.f, 0.f};
    #pragma unroll 1
    for (int gg = 0; gg < 4; ++gg) {
        const int kb = hh * 64 + gg * 16;
        float wl[16];
        #pragma unroll
        for (int u = 0; u < 16; ++u) wl[u] = w2[(kb + u) * 128 + f];
        #pragma unroll
        for (int u = 0; u < 16; ++u) {
            float4 hv = *(const float4*)&h1q[(kb + u) * 4];
            a2[0] = fmaf(hv.x, wl[u], a2[0]); a2[1] = fmaf(hv.y, wl[u], a2[1]);
            a2[2] = fmaf(hv.z, wl[u], a2[2]); a2[3] = fmaf(hv.w, wl[u], a2[3]);
        }
    }
    if (hh) {
        #pragma unroll
        for (int r = 0; r < 4; ++r) P[r * 128 + f] = a2[r];
    }
    __syncthreads();
    if (!hh) {
        #pragma unroll
        for (int r = 0; r < 4; ++r)
            H[(size_t)(r0 + r) * 128 + f] = a2[r] + P[r * 128 + f] + b2[f];
    }
}

// ---------------------------------------------------------------------------
// k_gcn1 = relation-mean aggregation + RGCN 3-matrix linear, fused.
// Block = (b, 4 target cols j). Masks (stride-12, b128-aligned) + counts
// inline; phase A split-i halves; phase B split-k halves; L2 loads 16-deep.
// ---------------------------------------------------------------------------
__global__ __launch_bounds__(256, 2) void k_gcn1(
        const float* __restrict__ A, const float* __restrict__ H,
        const float* __restrict__ Wrel, const float* __restrict__ Wroot,
        const float* __restrict__ bias, float* __restrict__ H2) {
    const int b  = blockIdx.x >> 6;
    const int j0 = (blockIdx.x & 63) * 4;
    const int t = threadIdx.x, f = t & 127, hh = t >> 7;
    __shared__ __align__(16) float ldsM[256 * 12];  // [i*12 + rel*4 + r]; alias P
    __shared__ __align__(16) float pb[128 * 12];    // [k*12 + {h4, m0_4, m1_4}]
    __shared__ float cntp[8 * 32];
    __shared__ float cnt[8];
    float* P = ldsM;
    const float* Ab = A + (size_t)b * NN * NN;
    const float* Hb = H + (size_t)b * NN * DV;

    { // masks: thread t owns row i=t (one float4 column-gather + 2 b128 stores)
        float4 a;
        a.x = Ab[(size_t)t * 256 + j0 + 0];
        a.y = Ab[(size_t)t * 256 + j0 + 1];
        a.z = Ab[(size_t)t * 256 + j0 + 2];
        a.w = Ab[(size_t)t * 256 + j0 + 3];
        float4 m0, m1;
        m0.x = (a.x < 0.f) ? 1.f : 0.f; m1.x = (a.x > 0.f) ? 1.f : 0.f;
        m0.y = (a.y < 0.f) ? 1.f : 0.f; m1.y = (a.y > 0.f) ? 1.f : 0.f;
        m0.z = (a.z < 0.f) ? 1.f : 0.f; m1.z = (a.z > 0.f) ? 1.f : 0.f;
        m0.w = (a.w < 0.f) ? 1.f : 0.f; m1.w = (a.w > 0.f) ? 1.f : 0.f;
        *(float4*)&ldsM[t * 12]     = m0;
        *(float4*)&ldsM[t * 12 + 4] = m1;
    }
    __syncthreads();
    { // count partials: 32 chunks x 8 slots
        int chunk = t >> 3, slot = t & 7;
        float c = 0.f;
        #pragma unroll
        for (int q = 0; q < 8; ++q) c += ldsM[(chunk * 8 + q) * 12 + slot];
        cntp[slot * 32 + chunk] = c;
    }
    // phase A: masked sums over i in [hh*128, hh*128+128)
    float acc[8] = {0.f, 0.f, 0.f, 0.f, 0.f, 0.f, 0.f, 0.f};
    #pragma unroll 1
    for (int gg = 0; gg < 8; ++gg) {
        const int ib = hh * 128 + gg * 16;
        float hv[16];
        #pragma unroll
        for (int u = 0; u < 16; ++u) hv[u] = Hb[(size_t)(ib + u) * 128 + f];
        #pragma unroll
        for (int u = 0; u < 16; ++u) {
            const float* mp = &ldsM[(ib + u) * 12];
            float4 m0 = *(const float4*)mp;
            float4 m1 = *(const float4*)(mp + 4);
            float h = hv[u];
            acc[0] = fmaf(m0.x, h, acc[0]); acc[1] = fmaf(m0.y, h, acc[1]);
            acc[2] = fmaf(m0.z, h, acc[2]); acc[3] = fmaf(m0.w, h, acc[3]);
            acc[4] = fmaf(m1.x, h, acc[4]); acc[5] = fmaf(m1.y, h, acc[5]);
            acc[6] = fmaf(m1.z, h, acc[6]); acc[7] = fmaf(m1.w, h, acc[7]);
        }
    }
    __syncthreads();   // phase A done; ldsM region becomes P
    if (hh) {
        #pragma unroll
        for (int s = 0; s < 8; ++s) P[s * 128 + f] = acc[s];
        float4 hrow;   // H rows j0..j0+3 for the root term
        hrow.x = Hb[(size_t)(j0 + 0) * 128 + f];
        hrow.y = Hb[(size_t)(j0 + 1) * 128 + f];
        hrow.z = Hb[(size_t)(j0 + 2) * 128 + f];
        hrow.w = Hb[(size_t)(j0 + 3) * 128 + f];
        *(float4*)&pb[f * 12] = hrow;
    }
    if (t < 8) {
        float s = 0.f;
        #pragma unroll
        for (int c = 0; c < 32; ++c) s += cntp[t * 32 + c];
        cnt[t] = s;
    }
    __syncthreads();
    if (!hh) {
        float4 q0, q1;
        q0.x = (acc[0] + P[0 * 128 + f]) / fmaxf(cnt[0], 1.f);
        q0.y = (acc[1] + P[1 * 128 + f]) / fmaxf(cnt[1], 1.f);
        q0.z = (acc[2] + P[2 * 128 + f]) / fmaxf(cnt[2], 1.f);
        q0.w = (acc[3] + P[3 * 128 + f]) / fmaxf(cnt[3], 1.f);
        q1.x = (acc[4] + P[4 * 128 + f]) / fmaxf(cnt[4], 1.f);
        q1.y = (acc[5] + P[5 * 128 + f]) / fmaxf(cnt[5], 1.f);
        q1.z = (acc[6] + P[6 * 128 + f]) / fmaxf(cnt[6], 1.f);
        q1.w = (acc[7] + P[7 * 128 + f]) / fmaxf(cnt[7], 1.f);
        *(float4*)&pb[f * 12 + 4] = q0;
        *(float4*)&pb[f * 12 + 8] = q1;
    }
    __syncthreads();
    // phase B: H2 = h@Wroot + m0@W0 + m1@W1 (+bias), split-k halves
    const float* W0 = Wrel;
    const float* W1 = Wrel + 128 * 128;
    float bc[4] = {0.f, 0.f, 0.f, 0.f};
    #pragma unroll 1
    for (int gg = 0; gg < 4; ++gg) {
        const int kb = hh * 64 + gg * 16;
        float wr[16], w0[16], w1[16];
        #pragma unroll
        for (int u = 0; u < 16; ++u) {
            wr[u] = Wroot[(kb + u) * 128 + f];
            w0[u] = W0[(kb + u) * 128 + f];
            w1[u] = W1[(kb + u) * 128 + f];
        }
        #pragma unroll
        for (int u = 0; u < 16; ++u) {
            const float* pk = &pb[(kb + u) * 12];
            float4 hv = *(const float4*)pk;
            float4 q0 = *(const float4*)(pk + 4);
            float4 q1 = *(const float4*)(pk + 8);
            bc[0] = fmaf(hv.x, wr[u], bc[0]); bc[0] = fmaf(q0.x, w0[u], bc[0]); bc[0] = fmaf(q1.x, w1[u], bc[0]);
            bc[1] = fmaf(hv.y, wr[u], bc[1]); bc[1] = fmaf(q0.y, w0[u], bc[1]); bc[1] = fmaf(q1.y, w1[u], bc[1]);
            bc[2] = fmaf(hv.z, wr[u], bc[2]); bc[2] = fmaf(q0.z, w0[u], bc[2]); bc[2] = fmaf(q1.z, w1[u], bc[2]);
            bc[3] = fmaf(hv.w, wr[u], bc[3]); bc[3] = fmaf(q0.w, w0[u], bc[3]); bc[3] = fmaf(q1.w, w1[u], bc[3]);
        }
    }
    if (hh) {
        #pragma unroll
        for (int r = 0; r < 4; ++r) P[r * 128 + f] = bc[r];
    }
    __syncthreads();
    if (!hh) {
        #pragma unroll
        for (int r = 0; r < 4; ++r)
            H2[(size_t)(b * 256 + j0 + r) * 128 + f] = bc[r] + P[r * 128 + f] + bias[f];
    }
}

// ---------------------------------------------------------------------------
// k_gcn2 = |A|-aggregation + LayerNorm + 2-layer MLP + H-update, fused.
// Block = (b, 4 source rows i). Split-j aggregation, split-k MLP.
// ---------------------------------------------------------------------------
__global__ __launch_bounds__(256, 2) void k_gcn2(
        const float* __restrict__ A, const float* __restrict__ H2,
        const float* __restrict__ g, const float* __restrict__ bta,
        const float* __restrict__ law, const float* __restrict__ lab,
        const float* __restrict__ lbw, const float* __restrict__ lbb,
        float* __restrict__ H) {
    const int b  = blockIdx.x >> 6;
    const int i0 = (blockIdx.x & 63) * 4;
    const int t = threadIdx.x, f = t & 127, hh = t >> 7;
    __shared__ __align__(16) float absA[256 * 4];  // [j*4 + r]; alias P (512 used)
    __shared__ __align__(16) float xq[128 * 4];
    __shared__ __align__(16) float uq[128 * 4];
    __shared__ float red[16];
    __shared__ float mi[8];
    float* P = absA;
    const float* Ab  = A + (size_t)b * NN * NN;
    const float* H2b = H2 + (size_t)b * NN * DV;

    { // |A| rows i0..i0+3, thread t owns column j=t (coalesced loads)
        float4 a;
        a.x = fabsf(Ab[(size_t)(i0 + 0) * 256 + t]);
        a.y = fabsf(Ab[(size_t)(i0 + 1) * 256 + t]);
        a.z = fabsf(Ab[(size_t)(i0 + 2) * 256 + t]);
        a.w = fabsf(Ab[(size_t)(i0 + 3) * 256 + t]);
        *(float4*)&absA[t * 4] = a;
    }
    __syncthreads();
    float acc[4] = {0.f, 0.f, 0.f, 0.f};
    #pragma unroll 1
    for (int gg = 0; gg < 8; ++gg) {
        const int jb = hh * 128 + gg * 16;
        float hv[16];
        #pragma unroll
        for (int u = 0; u < 16; ++u) hv[u] = H2b[(size_t)(jb + u) * 128 + f];
        #pragma unroll
        for (int u = 0; u < 16; ++u) {
            float4 av = *(const float4*)&absA[(jb + u) * 4];
            float h = hv[u];
            acc[0] = fmaf(av.x, h, acc[0]); acc[1] = fmaf(av.y, h, acc[1]);
            acc[2] = fmaf(av.z, h, acc[2]); acc[3] = fmaf(av.w, h, acc[3]);
        }
    }
    __syncthreads();   // absA dead -> P
    if (hh) {
        #pragma unroll
        for (int r = 0; r < 4; ++r) P[r * 128 + f] = acc[r];
    }
    __syncthreads();
    float x[4];
    if (!hh) {
        const int wv = t >> 6;
        #pragma unroll
        for (int r = 0; r < 4; ++r) {
            x[r] = acc[r] + P[r * 128 + f];
            float s = x[r], s2 = x[r] * x[r];
            #pragma unroll
            for (int o = 32; o > 0; o >>= 1) {
                s  += __shfl_down(s, o, 64);
                s2 += __shfl_down(s2, o, 64);
            }
            if ((t & 63) == 0) { red[r * 4 + wv * 2] = s; red[r * 4 + wv * 2 + 1] = s2; }
        }
    }
    __syncthreads();
    if (t < 4) {
        float s  = red[t * 4] + red[t * 4 + 2];
        float s2 = red[t * 4 + 1] + red[t * 4 + 3];
        float m = s * (1.f / 128.f);
        float v = s2 * (1.f / 128.f) - m * m;
        mi[t * 2] = m;
        mi[t * 2 + 1] = rsqrtf(v + 1e-5f);
    }
    __syncthreads();
    if (!hh) {
        float gf = g[f], bf = bta[f];
        float4 xv;
        xv.x = fmaxf((x[0] - mi[0]) * mi[1] * gf + bf, 0.f);
        xv.y = fmaxf((x[1] - mi[2]) * mi[3] * gf + bf, 0.f);
        xv.z = fmaxf((x[2] - mi[4]) * mi[5] * gf + bf, 0.f);
        xv.w = fmaxf((x[3] - mi[6]) * mi[7] * gf + bf, 0.f);
        *(float4*)&xq[f * 4] = xv;
    }
    __syncthreads();
    // MLP layer A (split-k)
    float u1[4] = {0.f, 0.f, 0.f, 0.f};
    #pragma unroll 1
    for (int gg = 0; gg < 4; ++gg) {
        const int kb = hh * 64 + gg * 16;
        float wl[16];
        #pragma unroll
        for (int u = 0; u < 16; ++u) wl[u] = law[(kb + u) * 128 + f];
        #pragma unroll
        for (int u = 0; u < 16; ++u) {
            float4 xv = *(const float4*)&xq[(kb + u) * 4];
            u1[0] = fmaf(xv.x, wl[u], u1[0]); u1[1] = fmaf(xv.y, wl[u], u1[1]);
            u1[2] = fmaf(xv.z, wl[u], u1[2]); u1[3] = fmaf(xv.w, wl[u], u1[3]);
        }
    }
    if (hh) {
        #pragma unroll
        for (int r = 0; r < 4; ++r) P[r * 128 + f] = u1[r];
    }
    __syncthreads();
    if (!hh) {
        float4 uv;
        uv.x = fmaxf(u1[0] + P[0 * 128 + f] + lab[f], 0.f);
        uv.y = fmaxf(u1[1] + P[1 * 128 + f] + lab[f], 0.f);
        uv.z = fmaxf(u1[2] + P[2 * 128 + f] + lab[f], 0.f);
        uv.w = fmaxf(u1[3] + P[3 * 128 + f] + lab[f], 0.f);
        *(float4*)&uq[f * 4] = uv;
    }
    __syncthreads();
    // MLP layer B (split-k)
    float u2[4] = {0.f, 0.f, 0.f, 0.f};
    #pragma unroll 1
    for (int gg = 0; gg < 4; ++gg) {
        const int kb = hh * 64 + gg * 16;
        float wl[16];
        #pragma unroll
        for (int u = 0; u < 16; ++u) wl[u] = lbw[(kb + u) * 128 + f];
        #pragma unroll
        for (int u = 0; u < 16; ++u) {
            float4 uv = *(const float4*)&uq[(kb + u) * 4];
            u2[0] = fmaf(uv.x, wl[u], u2[0]); u2[1] = fmaf(uv.y, wl[u], u2[1]);
            u2[2] = fmaf(uv.z, wl[u], u2[2]); u2[3] = fmaf(uv.w, wl[u], u2[3]);
        }
    }
    if (hh) {
        #pragma unroll
        for (int r = 0; r < 4; ++r) P[r * 128 + f] = u2[r];
    }
    __syncthreads();
    if (!hh) {
        #pragma unroll
        for (int r = 0; r < 4; ++r) {
            size_t o = (size_t)(b * 256 + i0 + r) * 128 + f;
            H[o] = H[o] + u2[r] + P[r * 128 + f] + lbb[f];
        }
    }
}

// ---------------------------------------------------------------------------
// k_deepset: phi (128->256->256 relu) + masked pooling. 4 rows/block,
// grid 512, 256 thr (f = t); weights streamed once per block, 16-deep.
// ---------------------------------------------------------------------------
__global__ __launch_bounds__(256, 2) void k_deepset(
        const float* __restrict__ H, const float* __restrict__ hm,
        const float* __restrict__ w1, const float* __restrict__ b1,
        const float* __restrict__ w2, const float* __restrict__ b2,
        float* __restrict__ hsum, float* __restrict__ asum) {
    const int r0 = blockIdx.x * 4;
    const int b  = blockIdx.x >> 6;
    const int t  = threadIdx.x;
    __shared__ __align__(16) float hq[128 * 4];
    __shared__ __align__(16) float ph[256 * 4];
    __shared__ float hmv[4];
    if (t < 128) {
        float4 v;
        v.x = H[(size_t)(r0 + 0) * 128 + t];
        v.y = H[(size_t)(r0 + 1) * 128 + t];
        v.z = H[(size_t)(r0 + 2) * 128 + t];
        v.w = H[(size_t)(r0 + 3) * 128 + t];
        *(float4*)&hq[t * 4] = v;
    }
    if (t >= 252) hmv[t - 252] = hm[r0 + (t - 252)];
    __syncthreads();
    float acc[4] = {0.f, 0.f, 0.f, 0.f};
    #pragma unroll 1
    for (int gg = 0; gg < 8; ++gg) {
        const int kb = gg * 16;
        float wl[16];
        #pragma unroll
        for (int u = 0; u < 16; ++u) wl[u] = w1[(kb + u) * 256 + t];
        #pragma unroll
        for (int u = 0; u < 16; ++u) {
            float4 hv = *(const float4*)&hq[(kb + u) * 4];
            acc[0] = fmaf(hv.x, wl[u], acc[0]); acc[1] = fmaf(hv.y, wl[u], acc[1]);
            acc[2] = fmaf(hv.z, wl[u], acc[2]); acc[3] = fmaf(hv.w, wl[u], acc[3]);
        }
    }
    {
        float bb = b1[t];
        float4 pv;
        pv.x = fmaxf(acc[0] + bb, 0.f); pv.y = fmaxf(acc[1] + bb, 0.f);
        pv.z = fmaxf(acc[2] + bb, 0.f); pv.w = fmaxf(acc[3] + bb, 0.f);
        *(float4*)&ph[t * 4] = pv;
    }
    __syncthreads();
    float a2[4] = {0.f, 0.f, 0.f, 0.f};
    #pragma unroll 1
    for (int gg = 0; gg < 16; ++gg) {
        const int kb = gg * 16;
        float wl[16];
        #pragma unroll
        for (int u = 0; u < 16; ++u) wl[u] = w2[(kb + u) * 256 + t];
        #pragma unroll
        for (int u = 0; u < 16; ++u) {
            float4 pv = *(const float4*)&ph[(kb + u) * 4];
            a2[0] = fmaf(pv.x, wl[u], a2[0]); a2[1] = fmaf(pv.y, wl[u], a2[1]);
            a2[2] = fmaf(pv.z, wl[u], a2[2]); a2[3] = fmaf(pv.w, wl[u], a2[3]);
        }
    }
    float bb = b2[t];
    float hp = 0.f, sp = 0.f;
    #pragma unroll
    for (int r = 0; r < 4; ++r) {
        float p = fmaxf(a2[r] + bb, 0.f);
        sp += p;
        hp = fmaf(p, hmv[r], hp);
    }
    atomicAdd(&hsum[b * 256 + t], hp);
    atomicAdd(&asum[b * 256 + t], sp - hp);
}

// ---------------------------------------------------------------------------
// k_rho: out[b] = 0.5 + 0.5*tanh(rho(home)-rho(away))
// ---------------------------------------------------------------------------
__global__ __launch_bounds__(128) void k_rho(const float* __restrict__ home_sum,
        const float* __restrict__ away_sum,
        const float* __restrict__ w1, const float* __restrict__ b1,
        const float* __restrict__ w2, const float* __restrict__ b2,
        float* __restrict__ out) {
    const int b = blockIdx.x;
    const int t = threadIdx.x;
    __shared__ float ws[2];
    float d[2];
    for (int which = 0; which < 2; ++which) {
        const float* s = (which == 0 ? home_sum : away_sum) + b * 256;
        float acc = b1[t];
        #pragma unroll 8
        for (int k = 0; k < 256; ++k) acc = fmaf(s[k], w1[k * 128 + t], acc);
        acc = fmaxf(acc, 0.f);
        float p = acc * w2[t];
        #pragma unroll
        for (int o = 32; o > 0; o >>= 1) p += __shfl_down(p, o, 64);
        if ((t & 63) == 0) ws[t >> 6] = p;
        __syncthreads();
        d[which] = ws[0] + ws[1] + b2[0];
        __syncthreads();
    }
    if (t == 0) out[b] = 0.5f + 0.5f * tanhf(d[0] - d[1]);
}

// ---------------------------------------------------------------------------
extern "C" void kernel_launch(void* const* d_in, const int* in_sizes, int n_in,
                              void* d_out, int out_size, void* d_ws, size_t ws_size,
                              hipStream_t stream) {
    const float* A         = (const float*)d_in[0];
    const float* X         = (const float*)d_in[1];
    const float* home_mask = (const float*)d_in[2];
    const float* emb1_w    = (const float*)d_in[3];
    const float* emb1_b    = (const float*)d_in[4];
    const float* emb2_w    = (const float*)d_in[5];
    const float* emb2_b    = (const float*)d_in[6];
    const float* rgcn_w[2]    = { (const float*)d_in[7],  (const float*)d_in[14] };
    const float* rgcn_root[2] = { (const float*)d_in[8],  (const float*)d_in[15] };
    const float* rgcn_bias[2] = { (const float*)d_in[9],  (const float*)d_in[16] };
    const float* lina_w[2]    = { (const float*)d_in[10], (const float*)d_in[17] };
    const float* lina_b[2]    = { (const float*)d_in[11], (const float*)d_in[18] };
    const float* linb_w[2]    = { (const float*)d_in[12], (const float*)d_in[19] };
    const float* linb_b[2]    = { (const float*)d_in[13], (const float*)d_in[20] };
    const float* norm_g  = (const float*)d_in[21];
    const float* norm_b  = (const float*)d_in[22];
    const float* phi_w1  = (const float*)d_in[23];
    const float* phi_b1  = (const float*)d_in[24];
    const float* phi_w2  = (const float*)d_in[25];
    const float* phi_b2  = (const float*)d_in[26];
    const float* rho_w1  = (const float*)d_in[27];
    const float* rho_b1  = (const float*)d_in[28];
    const float* rho_w2  = (const float*)d_in[29];
    const float* rho_b2  = (const float*)d_in[30];
    float* out = (float*)d_out;

    float* ws   = (float*)d_ws;
    float* H    = ws;               // 262144
    float* H2   = ws + 262144;      // 262144
    float* hsum = ws + 524288;      // 2048
    float* asum = ws + 526336;      // 2048 (contiguous with hsum)

    k_embed<<<512, 256, 0, stream>>>(X, emb1_w, emb1_b, emb2_w, emb2_b, H, hsum);

    for (int it = 0; it < 2; ++it) {
        k_gcn1<<<512, 256, 0, stream>>>(A, H, rgcn_w[it], rgcn_root[it],
                                        rgcn_bias[it], H2);
        k_gcn2<<<512, 256, 0, stream>>>(A, H2, norm_g, norm_b,
                                        lina_w[it], lina_b[it],
                                        linb_w[it], linb_b[it], H);
    }

    k_deepset<<<512, 256, 0, stream>>>(H, home_mask, phi_w1, phi_b1,
                                       phi_w2, phi_b2, hsum, asum);
    k_rho<<<NB, 128, 0, stream>>>(hsum, asum, rho_w1, rho_b1, rho_w2, rho_b2, out);
}

// Round 6
// 252.078 us; speedup vs baseline: 1.0682x; 1.0192x over previous
//
#include <hip/hip_runtime.h>
#include <math.h>

// Shapes: B=8, N=256, NID=64, V=GH=128, PHI=256, RHO=128
#define NB 8
#define NN 256
#define DV 128

// Async global->LDS DMA (16 B/lane). Per-wave: uniform base + lane*16.
typedef __attribute__((address_space(1))) const void* gas1p;
typedef __attribute__((address_space(3))) void* las3p;
static __device__ __forceinline__ void gld16(const float* g, float* l) {
    __builtin_amdgcn_global_load_lds((gas1p)g, (las3p)l, 16, 0, 0);
}

// ---------------------------------------------------------------------------
// k_embed: H = relu(X@w1+b1)@w2+b2.  4 rows/block, grid 512.
// Weights staged via global_load_lds in 8-k double-buffered tiles.
// Blocks 0..15 zero the pooling buffers.
// ---------------------------------------------------------------------------
__global__ __launch_bounds__(256, 2) void k_embed(const float* __restrict__ X,
        const float* __restrict__ w1, const float* __restrict__ b1,
        const float* __restrict__ w2, const float* __restrict__ b2,
        float* __restrict__ H, float* __restrict__ pools) {
    const int r0 = blockIdx.x * 4;
    const int t = threadIdx.x, f = t & 127, hh = t >> 7;
    const int lane = t & 63, wv = t >> 6;
    __shared__ __align__(16) float xq[64 * 4];     // [k][r]
    __shared__ __align__(16) float h1q[128 * 4];   // [k][r]
    __shared__ __align__(16) float P[4 * 128];
    __shared__ __align__(16) float wb[2 * 1024];   // 8k x 128 weight tiles
    if (blockIdx.x < 16) pools[blockIdx.x * 256 + t] = 0.f;
    // stage w1 tile 0 (async)
    { int off = wv * 256 + lane * 4; gld16(w1 + off, &wb[off]); }
    if (t < 64) {
        float4 v;
        v.x = X[(size_t)(r0 + 0) * 64 + t];
        v.y = X[(size_t)(r0 + 1) * 64 + t];
        v.z = X[(size_t)(r0 + 2) * 64 + t];
        v.w = X[(size_t)(r0 + 3) * 64 + t];
        *(float4*)&xq[t * 4] = v;
    }
    __syncthreads();
    float acc[4] = {0.f, 0.f, 0.f, 0.f};
    for (int kt = 0; kt < 8; ++kt) {           // K=64, 8 tiles of 8 k
        const int buf = kt & 1;
        if (kt < 7) {
            int off = wv * 256 + lane * 4;
            gld16(w1 + (kt + 1) * 1024 + off, &wb[(buf ^ 1) * 1024 + off]);
        }
        #pragma unroll
        for (int u = 0; u < 4; ++u) {
            int kL = u * 2 + hh;
            float w = wb[buf * 1024 + kL * 128 + f];
            float4 xv = *(const float4*)&xq[(kt * 8 + kL) * 4];
            acc[0] = fmaf(xv.x, w, acc[0]); acc[1] = fmaf(xv.y, w, acc[1]);
            acc[2] = fmaf(xv.z, w, acc[2]); acc[3] = fmaf(xv.w, w, acc[3]);
        }
        __syncthreads();
    }
    // stage w2 tile 0 into wb[0] (free), combine halves
    { int off = wv * 256 + lane * 4; gld16(w2 + off, &wb[off]); }
    if (hh) {
        #pragma unroll
        for (int r = 0; r < 4; ++r) P[r * 128 + f] = acc[r];
    }
    __syncthreads();
    if (!hh) {
        float bb = b1[f];
        float4 h;
        h.x = fmaxf(acc[0] + P[0 * 128 + f] + bb, 0.f);
        h.y = fmaxf(acc[1] + P[1 * 128 + f] + bb, 0.f);
        h.z = fmaxf(acc[2] + P[2 * 128 + f] + bb, 0.f);
        h.w = fmaxf(acc[3] + P[3 * 128 + f] + bb, 0.f);
        *(float4*)&h1q[f * 4] = h;
    }
    __syncthreads();
    float a2[4] = {0.f, 0.f, 0.f, 0.f};
    for (int kt = 0; kt < 16; ++kt) {          // K=128, 16 tiles
        const int buf = kt & 1;
        if (kt < 15) {
            int off = wv * 256 + lane * 4;
            gld16(w2 + (kt + 1) * 1024 + off, &wb[(buf ^ 1) * 1024 + off]);
        }
        #pragma unroll
        for (int u = 0; u < 4; ++u) {
            int kL = u * 2 + hh;
            float w = wb[buf * 1024 + kL * 128 + f];
            float4 hv = *(const float4*)&h1q[(kt * 8 + kL) * 4];
            a2[0] = fmaf(hv.x, w, a2[0]); a2[1] = fmaf(hv.y, w, a2[1]);
            a2[2] = fmaf(hv.z, w, a2[2]); a2[3] = fmaf(hv.w, w, a2[3]);
        }
        __syncthreads();
    }
    if (hh) {
        #pragma unroll
        for (int r = 0; r < 4; ++r) P[r * 128 + f] = a2[r];
    }
    __syncthreads();
    if (!hh) {
        #pragma unroll
        for (int r = 0; r < 4; ++r)
            H[(size_t)(r0 + r) * 128 + f] = a2[r] + P[r * 128 + f] + b2[f];
    }
}

// ---------------------------------------------------------------------------
// k_gcn1 = relation-mean aggregation + RGCN 3-matrix linear, fused.
// Block = (b, 4 target cols j). Phase A: H staged in 32-row double-buffered
// async tiles; masks = b128 broadcasts. Phase B: weights staged in 8-k tiles.
// ---------------------------------------------------------------------------
__global__ __launch_bounds__(256, 2) void k_gcn1(
        const float* __restrict__ A, const float* __restrict__ H,
        const float* __restrict__ Wrel, const float* __restrict__ Wroot,
        const float* __restrict__ bias, float* __restrict__ H2) {
    const int b  = blockIdx.x >> 6;
    const int j0 = (blockIdx.x & 63) * 4;
    const int t = threadIdx.x, f = t & 127, hh = t >> 7;
    const int lane = t & 63, wv = t >> 6;
    __shared__ __align__(16) float ldsH[2 * 4096];  // 32 KB: H tiles; later P + W tiles
    __shared__ __align__(16) float ldsM[256 * 8];   // masks [i*8 + rel*4 + r]
    __shared__ __align__(16) float pb[128 * 12];    // [k*12 + {h4, m0q, m1q}]
    __shared__ float cntp[256];
    __shared__ float cnt[8];
    float* P = ldsH;                                // combine region (1024 fl)
    const float* Ab = A + (size_t)b * 65536;
    const float* Hb = H + (size_t)b * 32768;
    const float* W0 = Wrel;
    const float* W1 = Wrel + 16384;

    // stage H tile 0 (rows 0..31) async
    {
        #pragma unroll
        for (int r = 0; r < 4; ++r) {
            int off = (r * 4 + wv) * 256 + lane * 4;
            gld16(Hb + off, &ldsH[off]);
        }
    }
    { // masks: thread t owns row i=t (contiguous float4)
        float4 a = *(const float4*)(Ab + (size_t)t * 256 + j0);
        float4 m0, m1;
        m0.x = (a.x < 0.f) ? 1.f : 0.f; m1.x = (a.x > 0.f) ? 1.f : 0.f;
        m0.y = (a.y < 0.f) ? 1.f : 0.f; m1.y = (a.y > 0.f) ? 1.f : 0.f;
        m0.z = (a.z < 0.f) ? 1.f : 0.f; m1.z = (a.z > 0.f) ? 1.f : 0.f;
        m0.w = (a.w < 0.f) ? 1.f : 0.f; m1.w = (a.w > 0.f) ? 1.f : 0.f;
        *(float4*)&ldsM[t * 8]     = m0;
        *(float4*)&ldsM[t * 8 + 4] = m1;
    }
    __syncthreads();
    { // count partials: 32 chunks x 8 slots
        int chunk = t >> 3, slot = t & 7;
        float c = 0.f;
        #pragma unroll
        for (int q = 0; q < 8; ++q) c += ldsM[(chunk * 8 + q) * 8 + slot];
        cntp[slot * 32 + chunk] = c;
    }
    // phase A: 8 tiles of 32 rows, halves split i within tile
    float acc[8] = {0.f, 0.f, 0.f, 0.f, 0.f, 0.f, 0.f, 0.f};
    for (int tl = 0; tl < 8; ++tl) {
        const int buf = tl & 1;
        if (tl < 7) {
            #pragma unroll
            for (int r = 0; r < 4; ++r) {
                int off = (r * 4 + wv) * 256 + lane * 4;
                gld16(Hb + (tl + 1) * 4096 + off, &ldsH[(buf ^ 1) * 4096 + off]);
            }
        }
        const float* hb = &ldsH[buf * 4096];
        #pragma unroll
        for (int u = 0; u < 16; ++u) {
            int iL = hh * 16 + u;
            int i  = tl * 32 + iL;
            float h = hb[iL * 128 + f];
            float4 m0 = *(const float4*)&ldsM[i * 8];
            float4 m1 = *(const float4*)&ldsM[i * 8 + 4];
            acc[0] = fmaf(m0.x, h, acc[0]); acc[1] = fmaf(m0.y, h, acc[1]);
            acc[2] = fmaf(m0.z, h, acc[2]); acc[3] = fmaf(m0.w, h, acc[3]);
            acc[4] = fmaf(m1.x, h, acc[4]); acc[5] = fmaf(m1.y, h, acc[5]);
            acc[6] = fmaf(m1.z, h, acc[6]); acc[7] = fmaf(m1.w, h, acc[7]);
        }
        __syncthreads();
    }
    // stage phase-B weight tile 0 (region disjoint from P)
    {
        #pragma unroll
        for (int r = 0; r < 3; ++r) {
            int c = r * 4 + wv;                    // 0..11
            const float* Wm = (c < 4) ? Wroot : ((c < 8) ? W0 : W1);
            int off = (c & 3) * 256 + lane * 4;
            gld16(Wm + off, &ldsH[1024 + ((c >> 2) * 1024) + off]);
        }
    }
    if (hh) {
        #pragma unroll
        for (int s = 0; s < 8; ++s) P[s * 128 + f] = acc[s];
        float4 hrow;
        hrow.x = Hb[(size_t)(j0 + 0) * 128 + f];
        hrow.y = Hb[(size_t)(j0 + 1) * 128 + f];
        hrow.z = Hb[(size_t)(j0 + 2) * 128 + f];
        hrow.w = Hb[(size_t)(j0 + 3) * 128 + f];
        *(float4*)&pb[f * 12] = hrow;
    }
    if (t < 8) {
        float s = 0.f;
        #pragma unroll
        for (int c = 0; c < 32; ++c) s += cntp[t * 32 + c];
        cnt[t] = s;
    }
    __syncthreads();
    if (!hh) {
        float4 q0, q1;
        q0.x = (acc[0] + P[0 * 128 + f]) / fmaxf(cnt[0], 1.f);
        q0.y = (acc[1] + P[1 * 128 + f]) / fmaxf(cnt[1], 1.f);
        q0.z = (acc[2] + P[2 * 128 + f]) / fmaxf(cnt[2], 1.f);
        q0.w = (acc[3] + P[3 * 128 + f]) / fmaxf(cnt[3], 1.f);
        q1.x = (acc[4] + P[4 * 128 + f]) / fmaxf(cnt[4], 1.f);
        q1.y = (acc[5] + P[5 * 128 + f]) / fmaxf(cnt[5], 1.f);
        q1.z = (acc[6] + P[6 * 128 + f]) / fmaxf(cnt[6], 1.f);
        q1.w = (acc[7] + P[7 * 128 + f]) / fmaxf(cnt[7], 1.f);
        *(float4*)&pb[f * 12 + 4] = q0;
        *(float4*)&pb[f * 12 + 8] = q1;
    }
    __syncthreads();
    // phase B: 16 tiles of 8 k; halves interleave k within tile
    float bc[4] = {0.f, 0.f, 0.f, 0.f};
    for (int kt = 0; kt < 16; ++kt) {
        const int buf = kt & 1;
        if (kt < 15) {
            #pragma unroll
            for (int r = 0; r < 3; ++r) {
                int c = r * 4 + wv;
                const float* Wm = (c < 4) ? Wroot : ((c < 8) ? W0 : W1);
                int off = (c & 3) * 256 + lane * 4;
                gld16(Wm + (kt + 1) * 1024 + off,
                      &ldsH[1024 + (buf ^ 1) * 3072 + ((c >> 2) * 1024) + off]);
            }
        }
        const float* wst = &ldsH[1024 + buf * 3072];
        #pragma unroll
        for (int u = 0; u < 4; ++u) {
            int kL = u * 2 + hh;
            int k  = kt * 8 + kL;
            float wr = wst[0 * 1024 + kL * 128 + f];
            float w0 = wst[1 * 1024 + kL * 128 + f];
            float w1 = wst[2 * 1024 + kL * 128 + f];
            const float* pk = &pb[k * 12];
            float4 hv = *(const float4*)pk;
            float4 q0 = *(const float4*)(pk + 4);
            float4 q1 = *(const float4*)(pk + 8);
            bc[0] = fmaf(hv.x, wr, bc[0]); bc[0] = fmaf(q0.x, w0, bc[0]); bc[0] = fmaf(q1.x, w1, bc[0]);
            bc[1] = fmaf(hv.y, wr, bc[1]); bc[1] = fmaf(q0.y, w0, bc[1]); bc[1] = fmaf(q1.y, w1, bc[1]);
            bc[2] = fmaf(hv.z, wr, bc[2]); bc[2] = fmaf(q0.z, w0, bc[2]); bc[2] = fmaf(q1.z, w1, bc[2]);
            bc[3] = fmaf(hv.w, wr, bc[3]); bc[3] = fmaf(q0.w, w0, bc[3]); bc[3] = fmaf(q1.w, w1, bc[3]);
        }
        __syncthreads();
    }
    if (hh) {
        #pragma unroll
        for (int r = 0; r < 4; ++r) P[r * 128 + f] = bc[r];
    }
    __syncthreads();
    if (!hh) {
        #pragma unroll
        for (int r = 0; r < 4; ++r)
            H2[(size_t)(b * 256 + j0 + r) * 128 + f] = bc[r] + P[r * 128 + f] + bias[f];
    }
}

// ---------------------------------------------------------------------------
// k_gcn2 = |A|-aggregation + LayerNorm + 2-layer MLP + H-update, fused.
// Same async-staging structure as gcn1.
// ---------------------------------------------------------------------------
__global__ __launch_bounds__(256, 2) void k_gcn2(
        const float* __restrict__ A, const float* __restrict__ H2,
        const float* __restrict__ g, const float* __restrict__ bta,
        const float* __restrict__ law, const float* __restrict__ lab,
        const float* __restrict__ lbw, const float* __restrict__ lbb,
        float* __restrict__ H) {
    const int b  = blockIdx.x >> 6;
    const int i0 = (blockIdx.x & 63) * 4;
    const int t = threadIdx.x, f = t & 127, hh = t >> 7;
    const int lane = t & 63, wv = t >> 6;
    __shared__ __align__(16) float ldsT[2 * 4096];  // H2 tiles; later P + W tiles
    __shared__ __align__(16) float absA[256 * 4];   // [j*4 + r]
    __shared__ __align__(16) float xq[128 * 4];
    __shared__ __align__(16) float uq[128 * 4];
    __shared__ float red[16];
    __shared__ float mi[8];
    float* P = ldsT;
    const float* Ab  = A + (size_t)b * 65536;
    const float* H2b = H2 + (size_t)b * 32768;

    {
        #pragma unroll
        for (int r = 0; r < 4; ++r) {
            int off = (r * 4 + wv) * 256 + lane * 4;
            gld16(H2b + off, &ldsT[off]);
        }
    }
    {
        float4 av;
        av.x = fabsf(Ab[(size_t)(i0 + 0) * 256 + t]);
        av.y = fabsf(Ab[(size_t)(i0 + 1) * 256 + t]);
        av.z = fabsf(Ab[(size_t)(i0 + 2) * 256 + t]);
        av.w = fabsf(Ab[(size_t)(i0 + 3) * 256 + t]);
        *(float4*)&absA[t * 4] = av;
    }
    __syncthreads();
    float acc[4] = {0.f, 0.f, 0.f, 0.f};
    for (int tl = 0; tl < 8; ++tl) {
        const int buf = tl & 1;
        if (tl < 7) {
            #pragma unroll
            for (int r = 0; r < 4; ++r) {
                int off = (r * 4 + wv) * 256 + lane * 4;
                gld16(H2b + (tl + 1) * 4096 + off, &ldsT[(buf ^ 1) * 4096 + off]);
            }
        }
        const float* hb = &ldsT[buf * 4096];
        #pragma unroll
        for (int u = 0; u < 16; ++u) {
            int jL = hh * 16 + u;
            int j  = tl * 32 + jL;
            float h = hb[jL * 128 + f];
            float4 av = *(const float4*)&absA[j * 4];
            acc[0] = fmaf(av.x, h, acc[0]); acc[1] = fmaf(av.y, h, acc[1]);
            acc[2] = fmaf(av.z, h, acc[2]); acc[3] = fmaf(av.w, h, acc[3]);
        }
        __syncthreads();
    }
    // stage law tile 0; combine halves + LayerNorm
    { int off = wv * 256 + lane * 4; gld16(law + off, &ldsT[1024 + off]); }
    if (hh) {
        #pragma unroll
        for (int r = 0; r < 4; ++r) P[r * 128 + f] = acc[r];
    }
    __syncthreads();
    float x[4];
    if (!hh) {
        const int wv2 = t >> 6;
        #pragma unroll
        for (int r = 0; r < 4; ++r) {
            x[r] = acc[r] + P[r * 128 + f];
            float s = x[r], s2 = x[r] * x[r];
            #pragma unroll
            for (int o = 32; o > 0; o >>= 1) {
                s  += __shfl_down(s, o, 64);
                s2 += __shfl_down(s2, o, 64);
            }
            if ((t & 63) == 0) { red[r * 4 + wv2 * 2] = s; red[r * 4 + wv2 * 2 + 1] = s2; }
        }
    }
    __syncthreads();
    if (t < 4) {
        float s  = red[t * 4] + red[t * 4 + 2];
        float s2 = red[t * 4 + 1] + red[t * 4 + 3];
        float m = s * (1.f / 128.f);
        float v = s2 * (1.f / 128.f) - m * m;
        mi[t * 2] = m;
        mi[t * 2 + 1] = rsqrtf(v + 1e-5f);
    }
    __syncthreads();
    if (!hh) {
        float gf = g[f], bf = bta[f];
        float4 xv;
        xv.x = fmaxf((x[0] - mi[0]) * mi[1] * gf + bf, 0.f);
        xv.y = fmaxf((x[1] - mi[2]) * mi[3] * gf + bf, 0.f);
        xv.z = fmaxf((x[2] - mi[4]) * mi[5] * gf + bf, 0.f);
        xv.w = fmaxf((x[3] - mi[6]) * mi[7] * gf + bf, 0.f);
        *(float4*)&xq[f * 4] = xv;
    }
    __syncthreads();
    // MLP layer A: 16 tiles of 8 k
    float u1[4] = {0.f, 0.f, 0.f, 0.f};
    for (int kt = 0; kt < 16; ++kt) {
        const int buf = kt & 1;
        if (kt < 15) {
            int off = wv * 256 + lane * 4;
            gld16(law + (kt + 1) * 1024 + off, &ldsT[1024 + (buf ^ 1) * 1024 + off]);
        }
        const float* wst = &ldsT[1024 + buf * 1024];
        #pragma unroll
        for (int u = 0; u < 4; ++u) {
            int kL = u * 2 + hh;
            float w = wst[kL * 128 + f];
            float4 xv = *(const float4*)&xq[(kt * 8 + kL) * 4];
            u1[0] = fmaf(xv.x, w, u1[0]); u1[1] = fmaf(xv.y, w, u1[1]);
            u1[2] = fmaf(xv.z, w, u1[2]); u1[3] = fmaf(xv.w, w, u1[3]);
        }
        __syncthreads();
    }
    { int off = wv * 256 + lane * 4; gld16(lbw + off, &ldsT[1024 + off]); }
    if (hh) {
        #pragma unroll
        for (int r = 0; r < 4; ++r) P[r * 128 + f] = u1[r];
    }
    __syncthreads();
    if (!hh) {
        float bb = lab[f];
        float4 uv;
        uv.x = fmaxf(u1[0] + P[0 * 128 + f] + bb, 0.f);
        uv.y = fmaxf(u1[1] + P[1 * 128 + f] + bb, 0.f);
        uv.z = fmaxf(u1[2] + P[2 * 128 + f] + bb, 0.f);
        uv.w = fmaxf(u1[3] + P[3 * 128 + f] + bb, 0.f);
        *(float4*)&uq[f * 4] = uv;
    }
    __syncthreads();
    // MLP layer B
    float u2[4] = {0.f, 0.f, 0.f, 0.f};
    for (int kt = 0; kt < 16; ++kt) {
        const int buf = kt & 1;
        if (kt < 15) {
            int off = wv * 256 + lane * 4;
            gld16(lbw + (kt + 1) * 1024 + off, &ldsT[1024 + (buf ^ 1) * 1024 + off]);
        }
        const float* wst = &ldsT[1024 + buf * 1024];
        #pragma unroll
        for (int u = 0; u < 4; ++u) {
            int kL = u * 2 + hh;
            float w = wst[kL * 128 + f];
            float4 uv = *(const float4*)&uq[(kt * 8 + kL) * 4];
            u2[0] = fmaf(uv.x, w, u2[0]); u2[1] = fmaf(uv.y, w, u2[1]);
            u2[2] = fmaf(uv.z, w, u2[2]); u2[3] = fmaf(uv.w, w, u2[3]);
        }
        __syncthreads();
    }
    if (hh) {
        #pragma unroll
        for (int r = 0; r < 4; ++r) P[r * 128 + f] = u2[r];
    }
    __syncthreads();
    if (!hh) {
        #pragma unroll
        for (int r = 0; r < 4; ++r) {
            size_t o = (size_t)(b * 256 + i0 + r) * 128 + f;
            H[o] = H[o] + u2[r] + P[r * 128 + f] + lbb[f];
        }
    }
}

// ---------------------------------------------------------------------------
// k_deepset: phi (128->256->256 relu) + masked pooling. 8 rows/block,
// grid 256, f = t; weights async-staged in 8-k double-buffered tiles.
// ---------------------------------------------------------------------------
__global__ __launch_bounds__(256, 2) void k_deepset(
        const float* __restrict__ H, const float* __restrict__ hm,
        const float* __restrict__ w1, const float* __restrict__ b1,
        const float* __restrict__ w2, const float* __restrict__ b2,
        float* __restrict__ hsum, float* __restrict__ asum) {
    const int r0 = blockIdx.x * 8;
    const int b  = blockIdx.x >> 5;
    const int t  = threadIdx.x;
    const int lane = t & 63, wv = t >> 6;
    __shared__ __align__(16) float hq[128 * 8];    // [k][r]
    __shared__ __align__(16) float ph[256 * 8];    // [k][r]
    __shared__ __align__(16) float dw[2 * 2048];   // 8k x 256 weight tiles
    __shared__ float hmv[8];
    // stage w1 tile 0
    {
        #pragma unroll
        for (int r = 0; r < 2; ++r) {
            int off = (r * 4 + wv) * 256 + lane * 4;
            gld16(w1 + off, &dw[off]);
        }
    }
    if (t < 128) {
        const float* Hr = H + (size_t)r0 * 128 + t;
        float4 h0, h1;
        h0.x = Hr[0 * 128]; h0.y = Hr[1 * 128]; h0.z = Hr[2 * 128]; h0.w = Hr[3 * 128];
        h1.x = Hr[4 * 128]; h1.y = Hr[5 * 128]; h1.z = Hr[6 * 128]; h1.w = Hr[7 * 128];
        *(float4*)&hq[t * 8]     = h0;
        *(float4*)&hq[t * 8 + 4] = h1;
    }
    if (t < 8) hmv[t] = hm[r0 + t];
    __syncthreads();
    float acc[8] = {0.f, 0.f, 0.f, 0.f, 0.f, 0.f, 0.f, 0.f};
    for (int kt = 0; kt < 16; ++kt) {          // K=128
        const int buf = kt & 1;
        if (kt < 15) {
            #pragma unroll
            for (int r = 0; r < 2; ++r) {
                int off = (r * 4 + wv) * 256 + lane * 4;
                gld16(w1 + (kt + 1) * 2048 + off, &dw[(buf ^ 1) * 2048 + off]);
            }
        }
        const float* wt = &dw[buf * 2048];
        #pragma unroll
        for (int u = 0; u < 8; ++u) {
            int k = kt * 8 + u;
            float w = wt[u * 256 + t];
            float4 hA = *(const float4*)&hq[k * 8];
            float4 hB = *(const float4*)&hq[k * 8 + 4];
            acc[0] = fmaf(hA.x, w, acc[0]); acc[1] = fmaf(hA.y, w, acc[1]);
            acc[2] = fmaf(hA.z, w, acc[2]); acc[3] = fmaf(hA.w, w, acc[3]);
            acc[4] = fmaf(hB.x, w, acc[4]); acc[5] = fmaf(hB.y, w, acc[5]);
            acc[6] = fmaf(hB.z, w, acc[6]); acc[7] = fmaf(hB.w, w, acc[7]);
        }
        __syncthreads();
    }
    // stage w2 tile 0; write ph
    {
        #pragma unroll
        for (int r = 0; r < 2; ++r) {
            int off = (r * 4 + wv) * 256 + lane * 4;
            gld16(w2 + off, &dw[off]);
        }
    }
    {
        float bb = b1[t];
        float4 p0, p1;
        p0.x = fmaxf(acc[0] + bb, 0.f); p0.y = fmaxf(acc[1] + bb, 0.f);
        p0.z = fmaxf(acc[2] + bb, 0.f); p0.w = fmaxf(acc[3] + bb, 0.f);
        p1.x = fmaxf(acc[4] + bb, 0.f); p1.y = fmaxf(acc[5] + bb, 0.f);
        p1.z = fmaxf(acc[6] + bb, 0.f); p1.w = fmaxf(acc[7] + bb, 0.f);
        *(float4*)&ph[t * 8]     = p0;
        *(float4*)&ph[t * 8 + 4] = p1;
    }
    __syncthreads();
    float a2[8] = {0.f, 0.f, 0.f, 0.f, 0.f, 0.f, 0.f, 0.f};
    for (int kt = 0; kt < 32; ++kt) {          // K=256
        const int buf = kt & 1;
        if (kt < 31) {
            #pragma unroll
            for (int r = 0; r < 2; ++r) {
                int off = (r * 4 + wv) * 256 + lane * 4;
                gld16(w2 + (kt + 1) * 2048 + off, &dw[(buf ^ 1) * 2048 + off]);
            }
        }
        const float* wt = &dw[buf * 2048];
        #pragma unroll
        for (int u = 0; u < 8; ++u) {
            int k = kt * 8 + u;
            float w = wt[u * 256 + t];
            float4 pA = *(const float4*)&ph[k * 8];
            float4 pB = *(const float4*)&ph[k * 8 + 4];
            a2[0] = fmaf(pA.x, w, a2[0]); a2[1] = fmaf(pA.y, w, a2[1]);
            a2[2] = fmaf(pA.z, w, a2[2]); a2[3] = fmaf(pA.w, w, a2[3]);
            a2[4] = fmaf(pB.x, w, a2[4]); a2[5] = fmaf(pB.y, w, a2[5]);
            a2[6] = fmaf(pB.z, w, a2[6]); a2[7] = fmaf(pB.w, w, a2[7]);
        }
        __syncthreads();
    }
    float bb = b2[t];
    float hp = 0.f, sp = 0.f;
    #pragma unroll
    for (int r = 0; r < 8; ++r) {
        float p = fmaxf(a2[r] + bb, 0.f);
        sp += p;
        hp = fmaf(p, hmv[r], hp);
    }
    atomicAdd(&hsum[b * 256 + t], hp);
    atomicAdd(&asum[b * 256 + t], sp - hp);
}

// ---------------------------------------------------------------------------
// k_rho: out[b] = 0.5 + 0.5*tanh(rho(home)-rho(away)); w1 async-staged,
// both branches computed per block (w1 streamed once). b2 cancels.
// ---------------------------------------------------------------------------
__global__ __launch_bounds__(256) void k_rho(const float* __restrict__ hsum,
        const float* __restrict__ asum,
        const float* __restrict__ w1, const float* __restrict__ b1,
        const float* __restrict__ w2, const float* __restrict__ b2,
        float* __restrict__ out) {
    const int b = blockIdx.x;
    const int t = threadIdx.x, f = t & 127, hh = t >> 7;
    const int lane = t & 63, wv = t >> 6;
    __shared__ __align__(16) float sv[512];
    __shared__ __align__(16) float wb[2 * 1024];
    __shared__ float P[2][128];
    __shared__ float red[4];
    { int off = wv * 256 + lane * 4; gld16(w1 + off, &wb[off]); }
    sv[t]       = hsum[b * 256 + t];
    sv[256 + t] = asum[b * 256 + t];
    __syncthreads();
    float ah = 0.f, aa = 0.f;
    for (int kt = 0; kt < 32; ++kt) {          // K=256
        const int buf = kt & 1;
        if (kt < 31) {
            int off = wv * 256 + lane * 4;
            gld16(w1 + (kt + 1) * 1024 + off, &wb[(buf ^ 1) * 1024 + off]);
        }
        #pragma unroll
        for (int u = 0; u < 4; ++u) {
            int kL = u * 2 + hh;
            float w = wb[buf * 1024 + kL * 128 + f];
            int k = kt * 8 + kL;
            ah = fmaf(sv[k], w, ah);
            aa = fmaf(sv[256 + k], w, aa);
        }
        __syncthreads();
    }
    if (hh) { P[0][f] = ah; P[1][f] = aa; }
    __syncthreads();
    if (!hh) {
        float bb = b1[f], w2f = w2[f];
        float ph = fmaxf(ah + P[0][f] + bb, 0.f) * w2f;
        float pa = fmaxf(aa + P[1][f] + bb, 0.f) * w2f;
        #pragma unroll
        for (int o = 32; o > 0; o >>= 1) {
            ph += __shfl_down(ph, o, 64);
            pa += __shfl_down(pa, o, 64);
        }
        if ((t & 63) == 0) { red[(t >> 6) * 2] = ph; red[(t >> 6) * 2 + 1] = pa; }
    }
    __syncthreads();
    if (t == 0)
        out[b] = 0.5f + 0.5f * tanhf((red[0] + red[2]) - (red[1] + red[3]));
}

// ---------------------------------------------------------------------------
extern "C" void kernel_launch(void* const* d_in, const int* in_sizes, int n_in,
                              void* d_out, int out_size, void* d_ws, size_t ws_size,
                              hipStream_t stream) {
    const float* A         = (const float*)d_in[0];
    const float* X         = (const float*)d_in[1];
    const float* home_mask = (const float*)d_in[2];
    const float* emb1_w    = (const float*)d_in[3];
    const float* emb1_b    = (const float*)d_in[4];
    const float* emb2_w    = (const float*)d_in[5];
    const float* emb2_b    = (const float*)d_in[6];
    const float* rgcn_w[2]    = { (const float*)d_in[7],  (const float*)d_in[14] };
    const float* rgcn_root[2] = { (const float*)d_in[8],  (const float*)d_in[15] };
    const float* rgcn_bias[2] = { (const float*)d_in[9],  (const float*)d_in[16] };
    const float* lina_w[2]    = { (const float*)d_in[10], (const float*)d_in[17] };
    const float* lina_b[2]    = { (const float*)d_in[11], (const float*)d_in[18] };
    const float* linb_w[2]    = { (const float*)d_in[12], (const float*)d_in[19] };
    const float* linb_b[2]    = { (const float*)d_in[13], (const float*)d_in[20] };
    const float* norm_g  = (const float*)d_in[21];
    const float* norm_b  = (const float*)d_in[22];
    const float* phi_w1  = (const float*)d_in[23];
    const float* phi_b1  = (const float*)d_in[24];
    const float* phi_w2  = (const float*)d_in[25];
    const float* phi_b2  = (const float*)d_in[26];
    const float* rho_w1  = (const float*)d_in[27];
    const float* rho_b1  = (const float*)d_in[28];
    const float* rho_w2  = (const float*)d_in[29];
    const float* rho_b2  = (const float*)d_in[30];
    float* out = (float*)d_out;

    float* ws   = (float*)d_ws;
    float* H    = ws;               // 262144
    float* H2   = ws + 262144;      // 262144
    float* hsum = ws + 524288;      // 2048
    float* asum = ws + 526336;      // 2048 (contiguous with hsum)

    k_embed<<<512, 256, 0, stream>>>(X, emb1_w, emb1_b, emb2_w, emb2_b, H, hsum);

    for (int it = 0; it < 2; ++it) {
        k_gcn1<<<512, 256, 0, stream>>>(A, H, rgcn_w[it], rgcn_root[it],
                                        rgcn_bias[it], H2);
        k_gcn2<<<512, 256, 0, stream>>>(A, H2, norm_g, norm_b,
                                        lina_w[it], lina_b[it],
                                        linb_w[it], linb_b[it], H);
    }

    k_deepset<<<256, 256, 0, stream>>>(H, home_mask, phi_w1, phi_b1,
                                       phi_w2, phi_b2, hsum, asum);
    k_rho<<<NB, 256, 0, stream>>>(hsum, asum, rho_w1, rho_b1, rho_w2, rho_b2, out);
}

// Round 7
// 207.094 us; speedup vs baseline: 1.3003x; 1.2172x over previous
//
#include <hip/hip_runtime.h>
#include <math.h>

// Shapes: B=8, N=256, NID=64, V=GH=128, PHI=256, RHO=128
#define NB 8
#define NN 256
#define DV 128

// Async global->LDS DMA (16 B/lane), lane-linear addressing.
typedef __attribute__((address_space(1))) const void* gas1p;
typedef __attribute__((address_space(3))) void* las3p;
static __device__ __forceinline__ void gld16(const float* g, float* l) {
    __builtin_amdgcn_global_load_lds((gas1p)g, (las3p)l, 16, 0, 0);
}

// ---------------------------------------------------------------------------
// k_embed: H = relu(X@w1+b1)@w2+b2. 4 rows/block, grid 512.
// f-quad layout: q = t&31 (features q*4..+3), u = t>>5 (K-slice of 8).
// Blocks 0..15 zero the pooling buffers.
// ---------------------------------------------------------------------------
__global__ __launch_bounds__(256, 2) void k_embed(const float* __restrict__ X,
        const float* __restrict__ w1, const float* __restrict__ b1,
        const float* __restrict__ w2, const float* __restrict__ b2,
        float* __restrict__ H, float* __restrict__ pools) {
    const int r0 = blockIdx.x * 4;
    const int t = threadIdx.x, q = t & 31, u = t >> 5;
    __shared__ __align__(16) float pool[12288];   // 48 KB
    __shared__ __align__(16) float xq[256];       // [k][r]
    __shared__ __align__(16) float h1q[512];      // [k][r]
    float* part = pool + 8192;                    // [u][r][f] = 4096
    if (blockIdx.x < 16) pools[blockIdx.x * 256 + t] = 0.f;
    // stage w1 (64x128) into pool[0..8192)
    #pragma unroll
    for (int rnd = 0; rnd < 8; ++rnd) {
        int idx = rnd * 256 + t;
        gld16(w1 + idx * 4, &pool[idx * 4]);
    }
    if (t < 64) {
        float4 v;
        v.x = X[(size_t)(r0 + 0) * 64 + t];
        v.y = X[(size_t)(r0 + 1) * 64 + t];
        v.z = X[(size_t)(r0 + 2) * 64 + t];
        v.w = X[(size_t)(r0 + 3) * 64 + t];
        *(float4*)&xq[t * 4] = v;
    }
    __syncthreads();
    {   // L1: K=64, thread covers k in [u*8, u*8+8)
        float acc[16];
        #pragma unroll
        for (int i = 0; i < 16; ++i) acc[i] = 0.f;
        #pragma unroll
        for (int kk = 0; kk < 8; ++kk) {
            int k = u * 8 + kk;
            float4 w4 = *(const float4*)&pool[k * 128 + q * 4];
            float wc[4] = {w4.x, w4.y, w4.z, w4.w};
            float4 x4 = *(const float4*)&xq[k * 4];
            float xr[4] = {x4.x, x4.y, x4.z, x4.w};
            #pragma unroll
            for (int r = 0; r < 4; ++r)
                #pragma unroll
                for (int c = 0; c < 4; ++c)
                    acc[r * 4 + c] = fmaf(xr[r], wc[c], acc[r * 4 + c]);
        }
        #pragma unroll
        for (int r = 0; r < 4; ++r)
            *(float4*)&part[u * 512 + r * 128 + q * 4] =
                make_float4(acc[r*4+0], acc[r*4+1], acc[r*4+2], acc[r*4+3]);
    }
    __syncthreads();
    // issue w2 tile 0 (32k x 128) into pool[0..4096); combine L1 meanwhile
    #pragma unroll
    for (int rnd = 0; rnd < 4; ++rnd) {
        int idx = rnd * 256 + t;
        gld16(w2 + idx * 4, &pool[idx * 4]);
    }
    if (t < 128) {
        int r = t >> 5, fq = t & 31;
        float4 s = *(const float4*)&b1[fq * 4];
        #pragma unroll
        for (int uu = 0; uu < 8; ++uu) {
            float4 p = *(const float4*)&part[uu * 512 + r * 128 + fq * 4];
            s.x += p.x; s.y += p.y; s.z += p.z; s.w += p.w;
        }
        h1q[(fq * 4 + 0) * 4 + r] = fmaxf(s.x, 0.f);
        h1q[(fq * 4 + 1) * 4 + r] = fmaxf(s.y, 0.f);
        h1q[(fq * 4 + 2) * 4 + r] = fmaxf(s.z, 0.f);
        h1q[(fq * 4 + 3) * 4 + r] = fmaxf(s.w, 0.f);
    }
    __syncthreads();
    // L2: K=128, 4 tiles of 32 k, dbuf pool[0..8192)
    float a2[16];
    #pragma unroll
    for (int i = 0; i < 16; ++i) a2[i] = 0.f;
    #pragma unroll 1
    for (int kt = 0; kt < 4; ++kt) {
        const int buf = kt & 1;
        if (kt < 3) {
            #pragma unroll
            for (int rnd = 0; rnd < 4; ++rnd) {
                int idx = rnd * 256 + t;
                gld16(w2 + (kt + 1) * 4096 + idx * 4,
                      &pool[(buf ^ 1) * 4096 + idx * 4]);
            }
        }
        const float* wt = &pool[buf * 4096];
        #pragma unroll
        for (int kk = 0; kk < 4; ++kk) {
            int kl = u * 4 + kk;
            float4 w4 = *(const float4*)&wt[kl * 128 + q * 4];
            float wc[4] = {w4.x, w4.y, w4.z, w4.w};
            float4 h4 = *(const float4*)&h1q[(kt * 32 + kl) * 4];
            float hr[4] = {h4.x, h4.y, h4.z, h4.w};
            #pragma unroll
            for (int r = 0; r < 4; ++r)
                #pragma unroll
                for (int c = 0; c < 4; ++c)
                    a2[r * 4 + c] = fmaf(hr[r], wc[c], a2[r * 4 + c]);
        }
        __syncthreads();
    }
    #pragma unroll
    for (int r = 0; r < 4; ++r)
        *(float4*)&part[u * 512 + r * 128 + q * 4] =
            make_float4(a2[r*4+0], a2[r*4+1], a2[r*4+2], a2[r*4+3]);
    __syncthreads();
    if (t < 128) {
        int r = t >> 5, fq = t & 31;
        float4 s = *(const float4*)&b2[fq * 4];
        #pragma unroll
        for (int uu = 0; uu < 8; ++uu) {
            float4 p = *(const float4*)&part[uu * 512 + r * 128 + fq * 4];
            s.x += p.x; s.y += p.y; s.z += p.z; s.w += p.w;
        }
        *(float4*)&H[(size_t)(r0 + r) * 128 + fq * 4] = s;
    }
}

// ---------------------------------------------------------------------------
// k_gcn1 = relation-mean aggregation + RGCN 3-matrix linear, fused.
// Block = (b, 4 targets j). Phase A: K=256 i, 8 async 32-i tiles, K-split-8.
// Phase B: K=128, 8 async 16-k weight tiles (3 mats), K-split-8.
// ---------------------------------------------------------------------------
__global__ __launch_bounds__(256, 2) void k_gcn1(
        const float* __restrict__ A, const float* __restrict__ H,
        const float* __restrict__ Wrel, const float* __restrict__ Wroot,
        const float* __restrict__ bias, float* __restrict__ H2) {
    const int b  = blockIdx.x >> 6;
    const int j0 = (blockIdx.x & 63) * 4;
    const int t = threadIdx.x, q = t & 31, u = t >> 5;
    __shared__ __align__(16) float pool[12288];   // 48 KB
    __shared__ __align__(16) float pb[1536];      // [k][h4|m0_4|m1_4]
    __shared__ float cntp[256];
    __shared__ float cnt[8];
    float* htile = pool;            // [2][4096] (phase A)
    float* maskM = pool + 8192;     // [256][8]  (phase A)
    float* part  = pool;            // [8][1024] (A-combine)
    const float* Ab = A + (size_t)b * 65536;
    const float* Hb = H + (size_t)b * 32768;
    const float* W0 = Wrel;
    const float* W1 = Wrel + 16384;

    #pragma unroll
    for (int rnd = 0; rnd < 4; ++rnd) {
        int idx = rnd * 256 + t;
        gld16(Hb + idx * 4, &htile[idx * 4]);
    }
    {   // masks: thread t owns row i=t
        float4 a = *(const float4*)(Ab + (size_t)t * 256 + j0);
        float4 m0, m1;
        m0.x = (a.x < 0.f) ? 1.f : 0.f; m1.x = (a.x > 0.f) ? 1.f : 0.f;
        m0.y = (a.y < 0.f) ? 1.f : 0.f; m1.y = (a.y > 0.f) ? 1.f : 0.f;
        m0.z = (a.z < 0.f) ? 1.f : 0.f; m1.z = (a.z > 0.f) ? 1.f : 0.f;
        m0.w = (a.w < 0.f) ? 1.f : 0.f; m1.w = (a.w > 0.f) ? 1.f : 0.f;
        *(float4*)&maskM[t * 8]     = m0;
        *(float4*)&maskM[t * 8 + 4] = m1;
    }
    __syncthreads();
    {   // count partials: 32 chunks x 8 slots
        int chunk = t >> 3, slot = t & 7;
        float c = 0.f;
        #pragma unroll
        for (int qq = 0; qq < 8; ++qq) c += maskM[(chunk * 8 + qq) * 8 + slot];
        cntp[slot * 32 + chunk] = c;
    }
    // phase A
    float acc0[16], acc1[16];
    #pragma unroll
    for (int i = 0; i < 16; ++i) { acc0[i] = 0.f; acc1[i] = 0.f; }
    #pragma unroll 1
    for (int tl = 0; tl < 8; ++tl) {
        const int buf = tl & 1;
        if (tl < 7) {
            #pragma unroll
            for (int rnd = 0; rnd < 4; ++rnd) {
                int idx = rnd * 256 + t;
                gld16(Hb + (tl + 1) * 4096 + idx * 4,
                      &htile[(buf ^ 1) * 4096 + idx * 4]);
            }
        }
        const float* hb = &htile[buf * 4096];
        #pragma unroll
        for (int ii = 0; ii < 4; ++ii) {
            int iL = u * 4 + ii;
            int i  = tl * 32 + iL;
            float4 h4 = *(const float4*)&hb[iL * 128 + q * 4];
            float hc[4] = {h4.x, h4.y, h4.z, h4.w};
            float4 m0 = *(const float4*)&maskM[i * 8];
            float4 m1 = *(const float4*)&maskM[i * 8 + 4];
            float mr0[4] = {m0.x, m0.y, m0.z, m0.w};
            float mr1[4] = {m1.x, m1.y, m1.z, m1.w};
            #pragma unroll
            for (int r = 0; r < 4; ++r)
                #pragma unroll
                for (int c = 0; c < 4; ++c) {
                    acc0[r * 4 + c] = fmaf(mr0[r], hc[c], acc0[r * 4 + c]);
                    acc1[r * 4 + c] = fmaf(mr1[r], hc[c], acc1[r * 4 + c]);
                }
        }
        __syncthreads();
    }
    // dump A partials (htile/mask regions dead)
    #pragma unroll
    for (int r = 0; r < 4; ++r) {
        *(float4*)&part[u * 1024 + r * 128 + q * 4] =
            make_float4(acc0[r*4+0], acc0[r*4+1], acc0[r*4+2], acc0[r*4+3]);
        *(float4*)&part[u * 1024 + (4 + r) * 128 + q * 4] =
            make_float4(acc1[r*4+0], acc1[r*4+1], acc1[r*4+2], acc1[r*4+3]);
    }
    if (t < 8) {
        float s = 0.f;
        #pragma unroll
        for (int c = 0; c < 32; ++c) s += cntp[t * 32 + c];
        cnt[t] = s;
    }
    __syncthreads();
    {   // A-combine -> means into pb (slot = rel*4+r)
        int slot = t >> 5, fq = t & 31;
        float4 s = make_float4(0.f, 0.f, 0.f, 0.f);
        #pragma unroll
        for (int uu = 0; uu < 8; ++uu) {
            float4 p = *(const float4*)&part[uu * 1024 + slot * 128 + fq * 4];
            s.x += p.x; s.y += p.y; s.z += p.z; s.w += p.w;
        }
        float rc = 1.f / fmaxf(cnt[slot], 1.f);
        pb[(fq * 4 + 0) * 12 + 4 + slot] = s.x * rc;
        pb[(fq * 4 + 1) * 12 + 4 + slot] = s.y * rc;
        pb[(fq * 4 + 2) * 12 + 4 + slot] = s.z * rc;
        pb[(fq * 4 + 3) * 12 + 4 + slot] = s.w * rc;
    }
    if (t < 128) {  // root rows -> pb
        int r = t >> 5, fq = t & 31;
        float4 g4 = *(const float4*)(Hb + (size_t)(j0 + r) * 128 + fq * 4);
        pb[(fq * 4 + 0) * 12 + r] = g4.x;
        pb[(fq * 4 + 1) * 12 + r] = g4.y;
        pb[(fq * 4 + 2) * 12 + r] = g4.z;
        pb[(fq * 4 + 3) * 12 + r] = g4.w;
    }
    __syncthreads();
    // stage W tile 0: 16k x 128 x 3 = 6144 fl -> pool[0..6144)
    #pragma unroll
    for (int rnd = 0; rnd < 6; ++rnd) {
        int idx = rnd * 256 + t;
        int mat = idx >> 9, rem = idx & 511;
        const float* Wm = (mat == 0) ? Wroot : ((mat == 1) ? W0 : W1);
        gld16(Wm + rem * 4, &pool[mat * 2048 + rem * 4]);
    }
    __syncthreads();
    // phase B
    float bcc[16];
    #pragma unroll
    for (int i = 0; i < 16; ++i) bcc[i] = 0.f;
    #pragma unroll 1
    for (int kt = 0; kt < 8; ++kt) {
        const int buf = kt & 1;
        if (kt < 7) {
            #pragma unroll
            for (int rnd = 0; rnd < 6; ++rnd) {
                int idx = rnd * 256 + t;
                int mat = idx >> 9, rem = idx & 511;
                const float* Wm = (mat == 0) ? Wroot : ((mat == 1) ? W0 : W1);
                gld16(Wm + (kt + 1) * 2048 + rem * 4,
                      &pool[(buf ^ 1) * 6144 + mat * 2048 + rem * 4]);
            }
        }
        const float* wt = &pool[buf * 6144];
        #pragma unroll
        for (int kk = 0; kk < 2; ++kk) {
            int kl = u * 2 + kk;
            int k  = kt * 16 + kl;
            float4 wr = *(const float4*)&wt[kl * 128 + q * 4];
            float4 wa = *(const float4*)&wt[2048 + kl * 128 + q * 4];
            float4 wb = *(const float4*)&wt[4096 + kl * 128 + q * 4];
            float wrc[4] = {wr.x, wr.y, wr.z, wr.w};
            float wac[4] = {wa.x, wa.y, wa.z, wa.w};
            float wbc[4] = {wb.x, wb.y, wb.z, wb.w};
            float4 hv = *(const float4*)&pb[k * 12];
            float4 q0 = *(const float4*)&pb[k * 12 + 4];
            float4 q1 = *(const float4*)&pb[k * 12 + 8];
            float hr[4] = {hv.x, hv.y, hv.z, hv.w};
            float m0r[4] = {q0.x, q0.y, q0.z, q0.w};
            float m1r[4] = {q1.x, q1.y, q1.z, q1.w};
            #pragma unroll
            for (int r = 0; r < 4; ++r)
                #pragma unroll
                for (int c = 0; c < 4; ++c) {
                    float v = bcc[r * 4 + c];
                    v = fmaf(hr[r], wrc[c], v);
                    v = fmaf(m0r[r], wac[c], v);
                    v = fmaf(m1r[r], wbc[c], v);
                    bcc[r * 4 + c] = v;
                }
        }
        __syncthreads();
    }
    float* bpart = pool;   // [8][4][128]
    #pragma unroll
    for (int r = 0; r < 4; ++r)
        *(float4*)&bpart[u * 512 + r * 128 + q * 4] =
            make_float4(bcc[r*4+0], bcc[r*4+1], bcc[r*4+2], bcc[r*4+3]);
    __syncthreads();
    if (t < 128) {
        int r = t >> 5, fq = t & 31;
        float4 s = *(const float4*)&bias[fq * 4];
        #pragma unroll
        for (int uu = 0; uu < 8; ++uu) {
            float4 p = *(const float4*)&bpart[uu * 512 + r * 128 + fq * 4];
            s.x += p.x; s.y += p.y; s.z += p.z; s.w += p.w;
        }
        *(float4*)&H2[(size_t)(b * 256 + j0 + r) * 128 + fq * 4] = s;
    }
}

// ---------------------------------------------------------------------------
// k_gcn2 = |A|-aggregation + LayerNorm + 2-layer MLP + H-update, fused.
// ---------------------------------------------------------------------------
__global__ __launch_bounds__(256, 2) void k_gcn2(
        const float* __restrict__ A, const float* __restrict__ H2,
        const float* __restrict__ g, const float* __restrict__ bta,
        const float* __restrict__ law, const float* __restrict__ lab,
        const float* __restrict__ lbw, const float* __restrict__ lbb,
        float* __restrict__ H) {
    const int b  = blockIdx.x >> 6;
    const int i0 = (blockIdx.x & 63) * 4;
    const int t = threadIdx.x, q = t & 31, u = t >> 5;
    __shared__ __align__(16) float pool[9216];    // 36 KB
    __shared__ __align__(16) float xq[512];       // [k][r]
    __shared__ __align__(16) float uq[512];       // [k][r]
    __shared__ float red[16];
    __shared__ float mi[8];
    float* tileb = pool;            // [2][4096]
    float* absA  = pool + 8192;     // [256][4]
    float* part  = pool;            // [8][4][128]
    const float* Ab  = A + (size_t)b * 65536;
    const float* H2b = H2 + (size_t)b * 32768;

    #pragma unroll
    for (int rnd = 0; rnd < 4; ++rnd) {
        int idx = rnd * 256 + t;
        gld16(H2b + idx * 4, &tileb[idx * 4]);
    }
    {
        float4 av;
        av.x = fabsf(Ab[(size_t)(i0 + 0) * 256 + t]);
        av.y = fabsf(Ab[(size_t)(i0 + 1) * 256 + t]);
        av.z = fabsf(Ab[(size_t)(i0 + 2) * 256 + t]);
        av.w = fabsf(Ab[(size_t)(i0 + 3) * 256 + t]);
        *(float4*)&absA[t * 4] = av;
    }
    __syncthreads();
    float acc[16];
    #pragma unroll
    for (int i = 0; i < 16; ++i) acc[i] = 0.f;
    #pragma unroll 1
    for (int tl = 0; tl < 8; ++tl) {
        const int buf = tl & 1;
        if (tl < 7) {
            #pragma unroll
            for (int rnd = 0; rnd < 4; ++rnd) {
                int idx = rnd * 256 + t;
                gld16(H2b + (tl + 1) * 4096 + idx * 4,
                      &tileb[(buf ^ 1) * 4096 + idx * 4]);
            }
        }
        const float* hb = &tileb[buf * 4096];
        #pragma unroll
        for (int jj = 0; jj < 4; ++jj) {
            int jL = u * 4 + jj;
            int j  = tl * 32 + jL;
            float4 h4 = *(const float4*)&hb[jL * 128 + q * 4];
            float hc[4] = {h4.x, h4.y, h4.z, h4.w};
            float4 a4 = *(const float4*)&absA[j * 4];
            float ar[4] = {a4.x, a4.y, a4.z, a4.w};
            #pragma unroll
            for (int r = 0; r < 4; ++r)
                #pragma unroll
                for (int c = 0; c < 4; ++c)
                    acc[r * 4 + c] = fmaf(ar[r], hc[c], acc[r * 4 + c]);
        }
        __syncthreads();
    }
    #pragma unroll
    for (int r = 0; r < 4; ++r)
        *(float4*)&part[u * 512 + r * 128 + q * 4] =
            make_float4(acc[r*4+0], acc[r*4+1], acc[r*4+2], acc[r*4+3]);
    __syncthreads();
    // issue law tile 0 (16k x 128) into pool[4096..6144)
    #pragma unroll
    for (int rnd = 0; rnd < 2; ++rnd) {
        int idx = rnd * 256 + t;
        gld16(law + idx * 4, &pool[4096 + idx * 4]);
    }
    // combine + LN (f = t for t<128)
    float x[4] = {0.f, 0.f, 0.f, 0.f};
    if (t < 128) {
        const int wv2 = t >> 6;
        #pragma unroll
        for (int r = 0; r < 4; ++r) {
            float s = 0.f;
            #pragma unroll
            for (int uu = 0; uu < 8; ++uu) s += part[uu * 512 + r * 128 + t];
            x[r] = s;
        }
        #pragma unroll
        for (int r = 0; r < 4; ++r) {
            float s = x[r], s2 = x[r] * x[r];
            #pragma unroll
            for (int o = 32; o > 0; o >>= 1) {
                s  += __shfl_down(s, o, 64);
                s2 += __shfl_down(s2, o, 64);
            }
            if ((t & 63) == 0) {
                red[r * 4 + wv2 * 2] = s;
                red[r * 4 + wv2 * 2 + 1] = s2;
            }
        }
    }
    __syncthreads();
    if (t < 4) {
        float s  = red[t * 4] + red[t * 4 + 2];
        float s2 = red[t * 4 + 1] + red[t * 4 + 3];
        float m = s * (1.f / 128.f);
        float v = s2 * (1.f / 128.f) - m * m;
        mi[t * 2] = m;
        mi[t * 2 + 1] = rsqrtf(v + 1e-5f);
    }
    __syncthreads();
    if (t < 128) {
        float gf = g[t], bf = bta[t];
        float4 xv;
        xv.x = fmaxf((x[0] - mi[0]) * mi[1] * gf + bf, 0.f);
        xv.y = fmaxf((x[1] - mi[2]) * mi[3] * gf + bf, 0.f);
        xv.z = fmaxf((x[2] - mi[4]) * mi[5] * gf + bf, 0.f);
        xv.w = fmaxf((x[3] - mi[6]) * mi[7] * gf + bf, 0.f);
        *(float4*)&xq[t * 4] = xv;
    }
    __syncthreads();
    // MLP layer A: K=128, 8 tiles of 16k, dbuf pool[4096..8192)
    float u1[16];
    #pragma unroll
    for (int i = 0; i < 16; ++i) u1[i] = 0.f;
    #pragma unroll 1
    for (int kt = 0; kt < 8; ++kt) {
        const int buf = kt & 1;
        if (kt < 7) {
            #pragma unroll
            for (int rnd = 0; rnd < 2; ++rnd) {
                int idx = rnd * 256 + t;
                gld16(law + (kt + 1) * 2048 + idx * 4,
                      &pool[4096 + (buf ^ 1) * 2048 + idx * 4]);
            }
        }
        const float* wt = &pool[4096 + buf * 2048];
        #pragma unroll
        for (int kk = 0; kk < 2; ++kk) {
            int kl = u * 2 + kk;
            int k  = kt * 16 + kl;
            float4 w4 = *(const float4*)&wt[kl * 128 + q * 4];
            float wc[4] = {w4.x, w4.y, w4.z, w4.w};
            float4 x4 = *(const float4*)&xq[k * 4];
            float xr[4] = {x4.x, x4.y, x4.z, x4.w};
            #pragma unroll
            for (int r = 0; r < 4; ++r)
                #pragma unroll
                for (int c = 0; c < 4; ++c)
                    u1[r * 4 + c] = fmaf(xr[r], wc[c], u1[r * 4 + c]);
        }
        __syncthreads();
    }
    #pragma unroll
    for (int r = 0; r < 4; ++r)
        *(float4*)&part[u * 512 + r * 128 + q * 4] =
            make_float4(u1[r*4+0], u1[r*4+1], u1[r*4+2], u1[r*4+3]);
    __syncthreads();
    // issue lbw tile 0
    #pragma unroll
    for (int rnd = 0; rnd < 2; ++rnd) {
        int idx = rnd * 256 + t;
        gld16(lbw + idx * 4, &pool[4096 + idx * 4]);
    }
    if (t < 128) {
        float bb = lab[t];
        float4 uv;
        float s0 = 0.f, s1 = 0.f, s2 = 0.f, s3 = 0.f;
        #pragma unroll
        for (int uu = 0; uu < 8; ++uu) {
            s0 += part[uu * 512 + 0 * 128 + t];
            s1 += part[uu * 512 + 1 * 128 + t];
            s2 += part[uu * 512 + 2 * 128 + t];
            s3 += part[uu * 512 + 3 * 128 + t];
        }
        uv.x = fmaxf(s0 + bb, 0.f);
        uv.y = fmaxf(s1 + bb, 0.f);
        uv.z = fmaxf(s2 + bb, 0.f);
        uv.w = fmaxf(s3 + bb, 0.f);
        *(float4*)&uq[t * 4] = uv;
    }
    __syncthreads();
    // MLP layer B
    float u2[16];
    #pragma unroll
    for (int i = 0; i < 16; ++i) u2[i] = 0.f;
    #pragma unroll 1
    for (int kt = 0; kt < 8; ++kt) {
        const int buf = kt & 1;
        if (kt < 7) {
            #pragma unroll
            for (int rnd = 0; rnd < 2; ++rnd) {
                int idx = rnd * 256 + t;
                gld16(lbw + (kt + 1) * 2048 + idx * 4,
                      &pool[4096 + (buf ^ 1) * 2048 + idx * 4]);
            }
        }
        const float* wt = &pool[4096 + buf * 2048];
        #pragma unroll
        for (int kk = 0; kk < 2; ++kk) {
            int kl = u * 2 + kk;
            int k  = kt * 16 + kl;
            float4 w4 = *(const float4*)&wt[kl * 128 + q * 4];
            float wc[4] = {w4.x, w4.y, w4.z, w4.w};
            float4 x4 = *(const float4*)&uq[k * 4];
            float xr[4] = {x4.x, x4.y, x4.z, x4.w};
            #pragma unroll
            for (int r = 0; r < 4; ++r)
                #pragma unroll
                for (int c = 0; c < 4; ++c)
                    u2[r * 4 + c] = fmaf(xr[r], wc[c], u2[r * 4 + c]);
        }
        __syncthreads();
    }
    #pragma unroll
    for (int r = 0; r < 4; ++r)
        *(float4*)&part[u * 512 + r * 128 + q * 4] =
            make_float4(u2[r*4+0], u2[r*4+1], u2[r*4+2], u2[r*4+3]);
    __syncthreads();
    if (t < 128) {
        int r = t >> 5, fq = t & 31;
        float4 s = *(const float4*)&lbb[fq * 4];
        #pragma unroll
        for (int uu = 0; uu < 8; ++uu) {
            float4 p = *(const float4*)&part[uu * 512 + r * 128 + fq * 4];
            s.x += p.x; s.y += p.y; s.z += p.z; s.w += p.w;
        }
        float4 hold = *(const float4*)(H + (size_t)(b * 256 + i0 + r) * 128 + fq * 4);
        s.x += hold.x; s.y += hold.y; s.z += hold.z; s.w += hold.w;
        *(float4*)&H[(size_t)(b * 256 + i0 + r) * 128 + fq * 4] = s;
    }
}

// ---------------------------------------------------------------------------
// k_deepset: phi (128->256->256 relu) + masked pooling. 8 rows/block,
// grid 256 (1 block/CU). q = t&63 (f-quad of 256), u = t>>6 (K-slice of 4).
// ---------------------------------------------------------------------------
__global__ __launch_bounds__(256) void k_deepset(
        const float* __restrict__ H, const float* __restrict__ hm,
        const float* __restrict__ w1, const float* __restrict__ b1,
        const float* __restrict__ w2, const float* __restrict__ b2,
        float* __restrict__ hsum, float* __restrict__ asum) {
    const int r0 = blockIdx.x * 8;
    const int b  = blockIdx.x >> 5;
    const int t  = threadIdx.x, q = t & 63, u = t >> 6;
    __shared__ __align__(16) float wt2[2][8192];   // 64 KB
    __shared__ __align__(16) float part[8192];     // [u][r][f] 4*8*256
    __shared__ __align__(16) float hraw[1024];     // [r][f]
    __shared__ __align__(16) float ph2[2048];      // [r][f]
    __shared__ float hmv[8];
    #pragma unroll
    for (int rnd = 0; rnd < 8; ++rnd) {
        int idx = rnd * 256 + t;
        gld16(w1 + idx * 4, &wt2[0][idx * 4]);
    }
    gld16(H + (size_t)r0 * 128 + t * 4, &hraw[t * 4]);
    if (t < 8) hmv[t] = hm[r0 + t];
    __syncthreads();
    float acc[32];
    #pragma unroll
    for (int i = 0; i < 32; ++i) acc[i] = 0.f;
    #pragma unroll 1
    for (int kt = 0; kt < 4; ++kt) {     // K=128, tiles of 32 k
        const int buf = kt & 1;
        if (kt < 3) {
            #pragma unroll
            for (int rnd = 0; rnd < 8; ++rnd) {
                int idx = rnd * 256 + t;
                gld16(w1 + (kt + 1) * 8192 + idx * 4, &wt2[buf ^ 1][idx * 4]);
            }
        }
        const float* wt = wt2[buf];
        #pragma unroll
        for (int kk = 0; kk < 8; ++kk) {
            int kl = u * 8 + kk;
            int k  = kt * 32 + kl;
            float4 w4 = *(const float4*)&wt[kl * 256 + q * 4];
            float wc[4] = {w4.x, w4.y, w4.z, w4.w};
            float hr[8];
            #pragma unroll
            for (int r = 0; r < 8; ++r) hr[r] = hraw[r * 128 + k];
            #pragma unroll
            for (int r = 0; r < 8; ++r)
                #pragma unroll
                for (int c = 0; c < 4; ++c)
                    acc[r * 4 + c] = fmaf(hr[r], wc[c], acc[r * 4 + c]);
        }
        __syncthreads();
    }
    #pragma unroll
    for (int r = 0; r < 8; ++r)
        *(float4*)&part[u * 2048 + r * 256 + q * 4] =
            make_float4(acc[r*4+0], acc[r*4+1], acc[r*4+2], acc[r*4+3]);
    __syncthreads();
    // stage w2 tile 0; combine1 -> ph2
    #pragma unroll
    for (int rnd = 0; rnd < 8; ++rnd) {
        int idx = rnd * 256 + t;
        gld16(w2 + idx * 4, &wt2[0][idx * 4]);
    }
    #pragma unroll
    for (int e = 0; e < 2; ++e) {
        int idx = e * 256 + t;
        int r = idx >> 6, fq = idx & 63;
        float4 s = *(const float4*)&b1[fq * 4];
        #pragma unroll
        for (int uu = 0; uu < 4; ++uu) {
            float4 p = *(const float4*)&part[uu * 2048 + r * 256 + fq * 4];
            s.x += p.x; s.y += p.y; s.z += p.z; s.w += p.w;
        }
        s.x = fmaxf(s.x, 0.f); s.y = fmaxf(s.y, 0.f);
        s.z = fmaxf(s.z, 0.f); s.w = fmaxf(s.w, 0.f);
        *(float4*)&ph2[r * 256 + fq * 4] = s;
    }
    __syncthreads();
    float a2[32];
    #pragma unroll
    for (int i = 0; i < 32; ++i) a2[i] = 0.f;
    #pragma unroll 1
    for (int kt = 0; kt < 8; ++kt) {     // K=256, tiles of 32 k
        const int buf = kt & 1;
        if (kt < 7) {
            #pragma unroll
            for (int rnd = 0; rnd < 8; ++rnd) {
                int idx = rnd * 256 + t;
                gld16(w2 + (kt + 1) * 8192 + idx * 4, &wt2[buf ^ 1][idx * 4]);
            }
        }
        const float* wt = wt2[buf];
        #pragma unroll
        for (int kk = 0; kk < 8; ++kk) {
            int kl = u * 8 + kk;
            int k  = kt * 32 + kl;
            float4 w4 = *(const float4*)&wt[kl * 256 + q * 4];
            float wc[4] = {w4.x, w4.y, w4.z, w4.w};
            float pr[8];
            #pragma unroll
            for (int r = 0; r < 8; ++r) pr[r] = ph2[r * 256 + k];
            #pragma unroll
            for (int r = 0; r < 8; ++r)
                #pragma unroll
                for (int c = 0; c < 4; ++c)
                    a2[r * 4 + c] = fmaf(pr[r], wc[c], a2[r * 4 + c]);
        }
        __syncthreads();
    }
    #pragma unroll
    for (int r = 0; r < 8; ++r)
        *(float4*)&part[u * 2048 + r * 256 + q * 4] =
            make_float4(a2[r*4+0], a2[r*4+1], a2[r*4+2], a2[r*4+3]);
    __syncthreads();
    {   // final combine + relu + masked pool (f = t)
        float bb = b2[t];
        float hp = 0.f, sp = 0.f;
        #pragma unroll
        for (int r = 0; r < 8; ++r) {
            float s = bb;
            #pragma unroll
            for (int uu = 0; uu < 4; ++uu) s += part[uu * 2048 + r * 256 + t];
            float p = fmaxf(s, 0.f);
            sp += p;
            hp = fmaf(p, hmv[r], hp);
        }
        atomicAdd(&hsum[b * 256 + t], hp);
        atomicAdd(&asum[b * 256 + t], sp - hp);
    }
}

// ---------------------------------------------------------------------------
// k_rho: out[b] = 0.5 + 0.5*tanh(rho(home)-rho(away)); b2 cancels.
// ---------------------------------------------------------------------------
__global__ __launch_bounds__(256) void k_rho(const float* __restrict__ hsum,
        const float* __restrict__ asum,
        const float* __restrict__ w1, const float* __restrict__ b1,
        const float* __restrict__ w2, const float* __restrict__ b2,
        float* __restrict__ out) {
    const int bIdx = blockIdx.x;
    const int t = threadIdx.x, q = t & 31, u = t >> 5;
    __shared__ __align__(16) float pool[10240];   // tiles dbuf 8192 + part 2048
    __shared__ __align__(16) float sv[512];
    __shared__ float wsv[2];
    float* part = pool + 8192;
    #pragma unroll
    for (int rnd = 0; rnd < 4; ++rnd) {
        int idx = rnd * 256 + t;
        gld16(w1 + idx * 4, &pool[idx * 4]);
    }
    sv[t] = hsum[bIdx * 256 + t];
    sv[256 + t] = asum[bIdx * 256 + t];
    __syncthreads();
    float aH[4] = {0.f, 0.f, 0.f, 0.f}, aA[4] = {0.f, 0.f, 0.f, 0.f};
    #pragma unroll 1
    for (int kt = 0; kt < 8; ++kt) {     // K=256, tiles of 32 k
        const int buf = kt & 1;
        if (kt < 7) {
            #pragma unroll
            for (int rnd = 0; rnd < 4; ++rnd) {
                int idx = rnd * 256 + t;
                gld16(w1 + (kt + 1) * 4096 + idx * 4,
                      &pool[(buf ^ 1) * 4096 + idx * 4]);
            }
        }
        const float* wt = &pool[buf * 4096];
        #pragma unroll
        for (int kk = 0; kk < 4; ++kk) {
            int kl = u * 4 + kk;
            int k  = kt * 32 + kl;
            float4 w4 = *(const float4*)&wt[kl * 128 + q * 4];
            float sh = sv[k], sa = sv[256 + k];
            aH[0] = fmaf(sh, w4.x, aH[0]); aA[0] = fmaf(sa, w4.x, aA[0]);
            aH[1] = fmaf(sh, w4.y, aH[1]); aA[1] = fmaf(sa, w4.y, aA[1]);
            aH[2] = fmaf(sh, w4.z, aH[2]); aA[2] = fmaf(sa, w4.z, aA[2]);
            aH[3] = fmaf(sh, w4.w, aH[3]); aA[3] = fmaf(sa, w4.w, aA[3]);
        }
        __syncthreads();
    }
    *(float4*)&part[u * 256 + q * 4]       = make_float4(aH[0], aH[1], aH[2], aH[3]);
    *(float4*)&part[u * 256 + 128 + q * 4] = make_float4(aA[0], aA[1], aA[2], aA[3]);
    __syncthreads();
    if (t < 64) {
        int vec = t >> 5, fq = t & 31;
        float4 s = make_float4(0.f, 0.f, 0.f, 0.f);
        #pragma unroll
        for (int uu = 0; uu < 8; ++uu) {
            float4 p = *(const float4*)&part[uu * 256 + vec * 128 + fq * 4];
            s.x += p.x; s.y += p.y; s.z += p.z; s.w += p.w;
        }
        float4 bb = *(const float4*)&b1[fq * 4];
        float4 w2q = *(const float4*)&w2[fq * 4];
        float p = fmaxf(s.x + bb.x, 0.f) * w2q.x
                + fmaxf(s.y + bb.y, 0.f) * w2q.y
                + fmaxf(s.z + bb.z, 0.f) * w2q.z
                + fmaxf(s.w + bb.w, 0.f) * w2q.w;
        #pragma unroll
        for (int o = 16; o > 0; o >>= 1) p += __shfl_down(p, o, 32);
        if ((t & 31) == 0) wsv[vec] = p;
    }
    __syncthreads();
    if (t == 0) out[bIdx] = 0.5f + 0.5f * tanhf(wsv[0] - wsv[1]);
}

// ---------------------------------------------------------------------------
extern "C" void kernel_launch(void* const* d_in, const int* in_sizes, int n_in,
                              void* d_out, int out_size, void* d_ws, size_t ws_size,
                              hipStream_t stream) {
    const float* A         = (const float*)d_in[0];
    const float* X         = (const float*)d_in[1];
    const float* home_mask = (const float*)d_in[2];
    const float* emb1_w    = (const float*)d_in[3];
    const float* emb1_b    = (const float*)d_in[4];
    const float* emb2_w    = (const float*)d_in[5];
    const float* emb2_b    = (const float*)d_in[6];
    const float* rgcn_w[2]    = { (const float*)d_in[7],  (const float*)d_in[14] };
    const float* rgcn_root[2] = { (const float*)d_in[8],  (const float*)d_in[15] };
    const float* rgcn_bias[2] = { (const float*)d_in[9],  (const float*)d_in[16] };
    const float* lina_w[2]    = { (const float*)d_in[10], (const float*)d_in[17] };
    const float* lina_b[2]    = { (const float*)d_in[11], (const float*)d_in[18] };
    const float* linb_w[2]    = { (const float*)d_in[12], (const float*)d_in[19] };
    const float* linb_b[2]    = { (const float*)d_in[13], (const float*)d_in[20] };
    const float* norm_g  = (const float*)d_in[21];
    const float* norm_b  = (const float*)d_in[22];
    const float* phi_w1  = (const float*)d_in[23];
    const float* phi_b1  = (const float*)d_in[24];
    const float* phi_w2  = (const float*)d_in[25];
    const float* phi_b2  = (const float*)d_in[26];
    const float* rho_w1  = (const float*)d_in[27];
    const float* rho_b1  = (const float*)d_in[28];
    const float* rho_w2  = (const float*)d_in[29];
    const float* rho_b2  = (const float*)d_in[30];
    float* out = (float*)d_out;

    float* ws   = (float*)d_ws;
    float* H    = ws;               // 262144
    float* H2   = ws + 262144;      // 262144
    float* hsum = ws + 524288;      // 2048
    float* asum = ws + 526336;      // 2048 (contiguous with hsum)

    k_embed<<<512, 256, 0, stream>>>(X, emb1_w, emb1_b, emb2_w, emb2_b, H, hsum);

    for (int it = 0; it < 2; ++it) {
        k_gcn1<<<512, 256, 0, stream>>>(A, H, rgcn_w[it], rgcn_root[it],
                                        rgcn_bias[it], H2);
        k_gcn2<<<512, 256, 0, stream>>>(A, H2, norm_g, norm_b,
                                        lina_w[it], lina_b[it],
                                        linb_w[it], linb_b[it], H);
    }

    k_deepset<<<256, 256, 0, stream>>>(H, home_mask, phi_w1, phi_b1,
                                       phi_w2, phi_b2, hsum, asum);
    k_rho<<<NB, 256, 0, stream>>>(hsum, asum, rho_w1, rho_b1, rho_w2, rho_b2, out);
}